// Round 1
// baseline (1166.368 us; speedup 1.0000x reference)
//
#include <hip/hip_runtime.h>
#include <hip/hip_bf16.h>

// Problem constants
#define BATCH 4
#define CDIM 256
#define HH 64
#define WW 64
#define HWSZ 4096          // 64*64
#define P2 1024            // 32*32 pooled pixels per batch
#define NH 8
#define HD 32
#define GS 8
#define SCALE 0.17677669529663687f
#define EPS_GN 1e-6f
#define EPS_LN 1e-5f

// ---------------- GroupNorm stats (two-stage, deterministic) ----------------
__global__ void gn_partial(const float* __restrict__ a, const float* __restrict__ a2,
                           int per_batch, int nblk, float* __restrict__ part)
{
    int bb  = blockIdx.x / nblk;
    int blk = blockIdx.x % nblk;
    const float* pa  = a  + (size_t)bb * per_batch;
    const float* pa2 = a2 ? a2 + (size_t)bb * per_batch : nullptr;
    int tid = threadIdx.x;
    float s = 0.f, s2 = 0.f;
    for (int i = blk * 256 + tid; i < per_batch; i += nblk * 256) {
        float v = pa[i];
        if (pa2) v += pa2[i];
        s += v; s2 += v * v;
    }
    __shared__ float ls[256], ls2[256];
    ls[tid] = s; ls2[tid] = s2; __syncthreads();
    for (int off = 128; off > 0; off >>= 1) {
        if (tid < off) { ls[tid] += ls[tid + off]; ls2[tid] += ls2[tid + off]; }
        __syncthreads();
    }
    if (tid == 0) {
        part[blockIdx.x * 2]     = ls[0];
        part[blockIdx.x * 2 + 1] = ls2[0];
    }
}

__global__ void gn_finalize(const float* __restrict__ part, int nblk, float inv_n,
                            float eps, float* __restrict__ stats, int nb)
{
    int b = threadIdx.x;
    if (b < nb) {
        float s = 0.f, s2 = 0.f;
        for (int i = 0; i < nblk; i++) {
            s  += part[(b * nblk + i) * 2];
            s2 += part[(b * nblk + i) * 2 + 1];
        }
        float m = s * inv_n;
        float v = s2 * inv_n - m * m;
        stats[b * 2]     = m;
        stats[b * 2 + 1] = rsqrtf(v + eps);
    }
}

// ---------------- grid_x = GN(x + gx) materialized ----------------
__global__ void add_norm(const float* __restrict__ x, const float* __restrict__ g,
                         const float* __restrict__ stats,
                         const float* __restrict__ w, const float* __restrict__ bb,
                         float* __restrict__ out)
{
    int i = blockIdx.x * 256 + threadIdx.x;   // exactly 4*2^20 threads launched
    int b = i >> 20;
    int c = (i >> 12) & 255;
    float m = stats[b * 2], r = stats[b * 2 + 1];
    out[i] = ((x[i] + g[i]) - m) * r * w[c] + bb[c];
}

// ---------------- conv1x1 GEMM: OUT[b,m,p] = sum_k normA(A[b,k,p]) * W[m,k] + bias[m]
#define BM 64
#define BN 64
#define BKK 16
__global__ __launch_bounds__(256) void gemm_conv(
    const float* __restrict__ A, const float* __restrict__ A2,
    const float* __restrict__ W, const float* __restrict__ bias,
    float* __restrict__ out, int K, int P, int OC,
    const float* __restrict__ stats, const float* __restrict__ nw,
    const float* __restrict__ nb)
{
    int b  = blockIdx.z;
    int p0 = blockIdx.x * BN;
    int m0 = blockIdx.y * BM;
    const float* Ab  = A + (size_t)b * K * P;
    const float* A2b = A2 ? A2 + (size_t)b * K * P : nullptr;
    float mean = 0.f, rstd = 1.f;
    if (stats) { mean = stats[b * 2]; rstd = stats[b * 2 + 1]; }

    __shared__ float As[BKK][BN];
    __shared__ float Ws[BM][BKK + 1];

    int tid = threadIdx.x;
    int tx = tid & 15, ty = tid >> 4;
    float acc[4][4] = {};

    for (int k0 = 0; k0 < K; k0 += BKK) {
        #pragma unroll
        for (int e = tid; e < BKK * BN; e += 256) {
            int kl = e >> 6, pl = e & 63;
            int kg = k0 + kl;
            float v = Ab[(size_t)kg * P + p0 + pl];
            if (A2b)  v += A2b[(size_t)kg * P + p0 + pl];
            if (stats) v = (v - mean) * rstd * nw[kg] + nb[kg];
            As[kl][pl] = v;
        }
        #pragma unroll
        for (int e = tid; e < BM * BKK; e += 256) {
            int ml = e >> 4, kl = e & 15;
            Ws[ml][kl] = W[(size_t)(m0 + ml) * K + k0 + kl];
        }
        __syncthreads();
        #pragma unroll
        for (int k = 0; k < BKK; k++) {
            float a[4], w[4];
            #pragma unroll
            for (int i = 0; i < 4; i++) a[i] = As[k][tx * 4 + i];
            #pragma unroll
            for (int j = 0; j < 4; j++) w[j] = Ws[ty * 4 + j][k];
            #pragma unroll
            for (int j = 0; j < 4; j++)
                #pragma unroll
                for (int i = 0; i < 4; i++) acc[j][i] += w[j] * a[i];
        }
        __syncthreads();
    }
    #pragma unroll
    for (int j = 0; j < 4; j++) {
        int m = m0 + ty * 4 + j;
        float bs = bias ? bias[m] : 0.f;
        float* orow = out + (size_t)b * OC * P + (size_t)m * P + p0;
        #pragma unroll
        for (int i = 0; i < 4; i++) orow[tx * 4 + i] = acc[j][i] + bs;
    }
}

// ---------------- NT GEMM for patch-merge reduction: OUT[b,m,p] = sum_k A[b*P+p,k]*W[m,k]
__global__ __launch_bounds__(256) void gemm_nt(
    const float* __restrict__ A,  // [B*P, K] row-major
    const float* __restrict__ W,  // [OC, K]
    float* __restrict__ out, int K, int P, int OC)
{
    int b  = blockIdx.z;
    int p0 = blockIdx.x * BN;
    int m0 = blockIdx.y * BM;
    const float* Ab = A + (size_t)b * P * K;
    __shared__ float As[BN][BKK + 1];
    __shared__ float Ws[BM][BKK + 1];
    int tid = threadIdx.x, tx = tid & 15, ty = tid >> 4;
    float acc[4][4] = {};
    for (int k0 = 0; k0 < K; k0 += BKK) {
        #pragma unroll
        for (int e = tid; e < BN * BKK; e += 256) {
            int pl = e >> 4, kl = e & 15;
            As[pl][kl] = Ab[(size_t)(p0 + pl) * K + k0 + kl];
        }
        #pragma unroll
        for (int e = tid; e < BM * BKK; e += 256) {
            int ml = e >> 4, kl = e & 15;
            Ws[ml][kl] = W[(size_t)(m0 + ml) * K + k0 + kl];
        }
        __syncthreads();
        #pragma unroll
        for (int k = 0; k < BKK; k++) {
            float a[4], w[4];
            #pragma unroll
            for (int i = 0; i < 4; i++) a[i] = As[tx * 4 + i][k];
            #pragma unroll
            for (int j = 0; j < 4; j++) w[j] = Ws[ty * 4 + j][k];
            #pragma unroll
            for (int j = 0; j < 4; j++)
                #pragma unroll
                for (int i = 0; i < 4; i++) acc[j][i] += w[j] * a[i];
        }
        __syncthreads();
    }
    #pragma unroll
    for (int j = 0; j < 4; j++) {
        int m = m0 + ty * 4 + j;
        float* orow = out + (size_t)b * OC * P + (size_t)m * P + p0;
        #pragma unroll
        for (int i = 0; i < 4; i++) orow[tx * 4 + i] = acc[j][i];
    }
}

// ---------------- local windowed attention (8x8 windows, 64 tokens, d=32) ----------------
__global__ __launch_bounds__(64) void local_attn(
    const float* __restrict__ qkv,  // [B, 768, 4096]
    float* __restrict__ gx)         // [B, 256, 4096]
{
    int win  = blockIdx.x;                 // b*512 + head*64 + gy*8 + gxc
    int gxc  = win & 7;
    int gy   = (win >> 3) & 7;
    int head = (win >> 6) & 7;
    int b    = win >> 9;
    int tid  = threadIdx.x;

    __shared__ float Ks[64 * 36];
    __shared__ float Vs[64 * 36];
    const float* base = qkv + (size_t)b * 768 * HWSZ;
    int qc = head * 32, kc = 256 + head * 32, vc = 512 + head * 32;

    for (int i = 0; i < 32; i++) {
        int e = i * 64 + tid;
        int d = i, t = tid;
        int pix = (gy * 8 + (t >> 3)) * 64 + gxc * 8 + (t & 7);
        Ks[t * 36 + d] = base[(size_t)(kc + d) * HWSZ + pix];
        Vs[t * 36 + d] = base[(size_t)(vc + d) * HWSZ + pix];
        (void)e;
    }
    int mypix = (gy * 8 + (tid >> 3)) * 64 + gxc * 8 + (tid & 7);
    float q[32];
    #pragma unroll
    for (int d = 0; d < 32; d++) q[d] = base[(size_t)(qc + d) * HWSZ + mypix] * SCALE;
    __syncthreads();

    float mmax = -1e30f, l = 0.f, o[32] = {};
    for (int j = 0; j < 64; j++) {
        float s = 0.f;
        #pragma unroll
        for (int d = 0; d < 32; d++) s += q[d] * Ks[j * 36 + d];
        float mn = fmaxf(mmax, s);
        float corr = __expf(mmax - mn);
        float pj = __expf(s - mn);
        l = l * corr + pj;
        #pragma unroll
        for (int d = 0; d < 32; d++) o[d] = o[d] * corr + pj * Vs[j * 36 + d];
        mmax = mn;
    }
    float inv = 1.f / l;
    float* gout = gx + (size_t)b * CDIM * HWSZ;
    #pragma unroll
    for (int d = 0; d < 32; d++)
        gout[(size_t)(head * 32 + d) * HWSZ + mypix] = o[d] * inv;
}

// ---------------- patch-merge layernorm: one block per pooled pixel ----------------
__global__ __launch_bounds__(256) void patch_merge_ln(
    const float* __restrict__ gxn,   // grid_x [B,256,4096]
    const float* __restrict__ lnw, const float* __restrict__ lnb,
    float* __restrict__ mn)          // [B*1024, 1024]
{
    int pix = blockIdx.x;            // b*1024 + op
    int b = pix >> 10, op = pix & 1023;
    int oh = op >> 5, ow = op & 31;
    int t = threadIdx.x;
    const float* base = gxn + (size_t)b * CDIM * HWSZ;
    float v[4];
    #pragma unroll
    for (int i = 0; i < 4; i++) {
        int h = 2 * oh + (i & 1);
        int w = 2 * ow + (i >> 1);
        v[i] = base[(size_t)t * HWSZ + h * 64 + w];
    }
    float s  = v[0] + v[1] + v[2] + v[3];
    float s2 = v[0]*v[0] + v[1]*v[1] + v[2]*v[2] + v[3]*v[3];
    __shared__ float ls[256], ls2[256];
    ls[t] = s; ls2[t] = s2; __syncthreads();
    for (int off = 128; off > 0; off >>= 1) {
        if (t < off) { ls[t] += ls[t + off]; ls2[t] += ls2[t + off]; }
        __syncthreads();
    }
    float mu  = ls[0] * (1.f / 1024.f);
    float var = ls2[0] * (1.f / 1024.f) - mu * mu;
    float r = rsqrtf(var + EPS_LN);
    float* orow = mn + (size_t)pix * 1024;
    #pragma unroll
    for (int i = 0; i < 4; i++) {
        int j = i * 256 + t;
        orow[j] = (v[i] - mu) * r * lnw[j] + lnb[j];
    }
}

// ---------------- global attention: 4096 queries attend to 1024 pooled KV ----------------
__global__ __launch_bounds__(256) void global_attn(
    const float* __restrict__ qg,   // [B, 256, 4096]
    const float* __restrict__ kv,   // [B, 512, 1024]  (k: ch 0..255, v: ch 256..511)
    float* __restrict__ go)         // [B, 256, 4096]
{
    int blk  = blockIdx.x;          // b*128 + head*16 + qt
    int qt   = blk & 15;
    int head = (blk >> 4) & 7;
    int b    = blk >> 7;
    int tid  = threadIdx.x;
    int p    = qt * 256 + tid;

    __shared__ float Ks[64 * 36];
    __shared__ float Vs[64 * 36];

    const float* qbase = qg + (size_t)b * CDIM * HWSZ + (size_t)(head * 32) * HWSZ + p;
    float q[32];
    #pragma unroll
    for (int d = 0; d < 32; d++) q[d] = qbase[(size_t)d * HWSZ] * SCALE;

    const float* kbase = kv + (size_t)b * 512 * P2 + (size_t)(head * 32) * P2;
    const float* vbase = kbase + 256 * P2;

    float mmax = -1e30f, l = 0.f, o[32] = {};
    for (int kk = 0; kk < 1024; kk += 64) {
        __syncthreads();
        #pragma unroll
        for (int i = 0; i < 8; i++) {
            int e = i * 256 + tid;
            int d = e >> 6, j = e & 63;
            Ks[j * 36 + d] = kbase[(size_t)d * P2 + kk + j];
            Vs[j * 36 + d] = vbase[(size_t)d * P2 + kk + j];
        }
        __syncthreads();
        for (int j = 0; j < 64; j++) {
            float s = 0.f;
            #pragma unroll
            for (int d = 0; d < 32; d++) s += q[d] * Ks[j * 36 + d];
            float mn = fmaxf(mmax, s);
            float corr = __expf(mmax - mn);
            float pj = __expf(s - mn);
            l = l * corr + pj;
            #pragma unroll
            for (int d = 0; d < 32; d++) o[d] = o[d] * corr + pj * Vs[j * 36 + d];
            mmax = mn;
        }
    }
    float inv = 1.f / l;
    float* obase = go + (size_t)b * CDIM * HWSZ + (size_t)(head * 32) * HWSZ + p;
    #pragma unroll
    for (int d = 0; d < 32; d++) obase[(size_t)d * HWSZ] = o[d] * inv;
}

// ---------------- launcher ----------------
extern "C" void kernel_launch(void* const* d_in, const int* in_sizes, int n_in,
                              void* d_out, int out_size, void* d_ws, size_t ws_size,
                              hipStream_t stream)
{
    const float* x           = (const float*)d_in[0];
    const float* norm_w      = (const float*)d_in[1];
    const float* norm_b      = (const float*)d_in[2];
    const float* qkv_w       = (const float*)d_in[3];
    const float* qkv_b       = (const float*)d_in[4];
    const float* proj_w      = (const float*)d_in[5];
    const float* proj_b      = (const float*)d_in[6];
    const float* grid_norm_w = (const float*)d_in[7];
    const float* grid_norm_b = (const float*)d_in[8];
    const float* pm_ln_w     = (const float*)d_in[9];
    const float* pm_ln_b     = (const float*)d_in[10];
    const float* pm_red_w    = (const float*)d_in[11];
    const float* ds_norm_w   = (const float*)d_in[12];
    const float* ds_norm_b   = (const float*)d_in[13];
    const float* q_w         = (const float*)d_in[14];
    const float* q_b         = (const float*)d_in[15];
    const float* kv_w        = (const float*)d_in[16];
    const float* kv_b        = (const float*)d_in[17];
    float* out = (float*)d_out;

    float* wsf = (float*)d_ws;
    // region 0: 12.58M floats — qkvbuf, later reused as mn / qgbuf / gobuf
    float* qkvbuf = wsf;                       // [4,768,4096]
    float* mnbuf  = wsf;                       // [4096,1024]  (qkv dead)
    float* qgbuf  = wsf + 4194304;             // [4,256,4096]
    float* gobuf  = wsf + 8388608;             // [4,256,4096]
    // region 1: 4.19M floats — gx, later reused as pm + kv
    float* gxbuf  = wsf + 12582912;            // [4,256,4096]
    float* pmbuf  = wsf + 12582912;            // [4,256,1024] (gx dead)
    float* kvbuf  = wsf + 12582912 + 1048576;  // [4,512,1024]
    // region 2: grid_x (live to the end)
    float* gridx  = wsf + 16777216;            // [4,256,4096]
    // small scratch
    float* part   = wsf + 20971520;            // 512 floats
    float* stats0 = part + 512;
    float* stats1 = stats0 + 8;
    float* stats2 = stats1 + 8;

    // 1. stats of x (GN over C*H*W per batch)
    gn_partial<<<BATCH * 64, 256, 0, stream>>>(x, nullptr, 1048576, 64, part);
    gn_finalize<<<1, 64, 0, stream>>>(part, 64, 1.f / 1048576.f, EPS_GN, stats0, BATCH);
    // 2. qkv conv (norm folded into A-load)
    gemm_conv<<<dim3(64, 12, BATCH), 256, 0, stream>>>(
        x, nullptr, qkv_w, qkv_b, qkvbuf, 256, 4096, 768, stats0, norm_w, norm_b);
    // 3. local windowed attention -> gx
    local_attn<<<2048, 64, 0, stream>>>(qkvbuf, gxbuf);
    // 4. stats of x+gx
    gn_partial<<<BATCH * 64, 256, 0, stream>>>(x, gxbuf, 1048576, 64, part);
    gn_finalize<<<1, 64, 0, stream>>>(part, 64, 1.f / 1048576.f, EPS_GN, stats1, BATCH);
    // 5. grid_x = GN(x+gx)
    add_norm<<<16384, 256, 0, stream>>>(x, gxbuf, stats1, grid_norm_w, grid_norm_b, gridx);
    // 6. patch-merge layernorm rows
    patch_merge_ln<<<4096, 256, 0, stream>>>(gridx, pm_ln_w, pm_ln_b, mnbuf);
    // 7. patch-merge reduction GEMM
    gemm_nt<<<dim3(16, 4, BATCH), 256, 0, stream>>>(mnbuf, pm_red_w, pmbuf, 1024, 1024, 256);
    // 8. stats of pm
    gn_partial<<<BATCH * 16, 256, 0, stream>>>(pmbuf, nullptr, 262144, 16, part);
    gn_finalize<<<1, 64, 0, stream>>>(part, 16, 1.f / 262144.f, EPS_GN, stats2, BATCH);
    // 9. kv conv (ds-norm folded into A-load)
    gemm_conv<<<dim3(16, 8, BATCH), 256, 0, stream>>>(
        pmbuf, nullptr, kv_w, kv_b, kvbuf, 256, 1024, 512, stats2, ds_norm_w, ds_norm_b);
    // 10. q conv on grid_x
    gemm_conv<<<dim3(64, 4, BATCH), 256, 0, stream>>>(
        gridx, nullptr, q_w, q_b, qgbuf, 256, 4096, 256, nullptr, nullptr, nullptr);
    // 11. global attention -> go
    global_attn<<<512, 256, 0, stream>>>(qgbuf, kvbuf, gobuf);
    // 12. proj conv on (go + grid_x) -> out
    gemm_conv<<<dim3(64, 4, BATCH), 256, 0, stream>>>(
        gobuf, gridx, proj_w, proj_b, out, 256, 4096, 256, nullptr, nullptr, nullptr);
}

// Round 2
// 680.162 us; speedup vs baseline: 1.7148x; 1.7148x over previous
//
#include <hip/hip_runtime.h>
#include <hip/hip_bf16.h>

// Problem constants
#define BATCH 4
#define CDIM 256
#define HWSZ 4096          // 64*64
#define P2 1024            // 32*32 pooled pixels per batch
#define SCALE 0.17677669529663687f
#define EPS_GN 1e-6f
#define EPS_LN 1e-5f

typedef short v8s __attribute__((ext_vector_type(8)));
typedef float v4f __attribute__((ext_vector_type(4)));

__device__ __forceinline__ unsigned short f2bf(float f) {
    __hip_bfloat16 h = __float2bfloat16(f);
    return *reinterpret_cast<unsigned short*>(&h);
}

// ---------------- GroupNorm stats (two-stage, deterministic) ----------------
__global__ void gn_partial(const float* __restrict__ a, const float* __restrict__ a2,
                           int per_batch, int nblk, float* __restrict__ part)
{
    int bb  = blockIdx.x / nblk;
    int blk = blockIdx.x % nblk;
    const float* pa  = a  + (size_t)bb * per_batch;
    const float* pa2 = a2 ? a2 + (size_t)bb * per_batch : nullptr;
    int tid = threadIdx.x;
    float s = 0.f, s2 = 0.f;
    for (int i = blk * 256 + tid; i < per_batch; i += nblk * 256) {
        float v = pa[i];
        if (pa2) v += pa2[i];
        s += v; s2 += v * v;
    }
    __shared__ float ls[256], ls2[256];
    ls[tid] = s; ls2[tid] = s2; __syncthreads();
    for (int off = 128; off > 0; off >>= 1) {
        if (tid < off) { ls[tid] += ls[tid + off]; ls2[tid] += ls2[tid + off]; }
        __syncthreads();
    }
    if (tid == 0) {
        part[blockIdx.x * 2]     = ls[0];
        part[blockIdx.x * 2 + 1] = ls2[0];
    }
}

__global__ void gn_finalize(const float* __restrict__ part, int nblk, float inv_n,
                            float eps, float* __restrict__ stats, int nb)
{
    int b = threadIdx.x;
    if (b < nb) {
        float s = 0.f, s2 = 0.f;
        for (int i = 0; i < nblk; i++) {
            s  += part[(b * nblk + i) * 2];
            s2 += part[(b * nblk + i) * 2 + 1];
        }
        float m = s * inv_n;
        float v = s2 * inv_n - m * m;
        stats[b * 2]     = m;
        stats[b * 2 + 1] = rsqrtf(v + eps);
    }
}

// ---------------- grid_x = GN(x + gx) materialized ----------------
__global__ void add_norm(const float* __restrict__ x, const float* __restrict__ g,
                         const float* __restrict__ stats,
                         const float* __restrict__ w, const float* __restrict__ bb,
                         float* __restrict__ out)
{
    int i = blockIdx.x * 256 + threadIdx.x;
    int b = i >> 20;
    int c = (i >> 12) & 255;
    float m = stats[b * 2], r = stats[b * 2 + 1];
    out[i] = ((x[i] + g[i]) - m) * r * w[c] + bb[c];
}

// ---------------- conv1x1 GEMM: OUT[b,m,p] = sum_k normA(A[b,k,p]) * W[m,k] + bias[m]
// AT=true: A is [b][p][K] row-major (transposed), A2 (if set) stays [b][K][p].
#define BM 64
#define BN 64
#define BKK 16
template<bool AT>
__global__ __launch_bounds__(256) void gemm_conv(
    const float* __restrict__ A, const float* __restrict__ A2,
    const float* __restrict__ W, const float* __restrict__ bias,
    float* __restrict__ out, int K, int P, int OC,
    const float* __restrict__ stats, const float* __restrict__ nw,
    const float* __restrict__ nb)
{
    int b  = blockIdx.z;
    int p0 = blockIdx.x * BN;
    int m0 = blockIdx.y * BM;
    const float* Ab  = A + (size_t)b * K * P;
    const float* A2b = A2 ? A2 + (size_t)b * K * P : nullptr;
    float mean = 0.f, rstd = 1.f;
    if (stats) { mean = stats[b * 2]; rstd = stats[b * 2 + 1]; }

    __shared__ float As[BKK][BN + 4];
    __shared__ float Ws[BM][BKK + 1];

    int tid = threadIdx.x;
    int tx = tid & 15, ty = tid >> 4;
    float acc[4][4] = {};

    for (int k0 = 0; k0 < K; k0 += BKK) {
        if (AT) {
            // stage A2 (channel-major) with coalesced mapping
            #pragma unroll
            for (int e = tid; e < BKK * BN; e += 256) {
                int kl = e >> 6, pl = e & 63;
                As[kl][pl] = A2b ? A2b[(size_t)(k0 + kl) * P + p0 + pl] : 0.f;
            }
            __syncthreads();
            // add transposed A ([p][K] row-major) with coalesced mapping
            #pragma unroll
            for (int e = tid; e < BKK * BN; e += 256) {
                int pl = e >> 4, kl = e & 15;
                As[kl][pl] += Ab[(size_t)(p0 + pl) * K + k0 + kl];
            }
        } else {
            #pragma unroll
            for (int e = tid; e < BKK * BN; e += 256) {
                int kl = e >> 6, pl = e & 63;
                int kg = k0 + kl;
                float v = Ab[(size_t)kg * P + p0 + pl];
                if (A2b)  v += A2b[(size_t)kg * P + p0 + pl];
                if (stats) v = (v - mean) * rstd * nw[kg] + nb[kg];
                As[kl][pl] = v;
            }
        }
        #pragma unroll
        for (int e = tid; e < BM * BKK; e += 256) {
            int ml = e >> 4, kl = e & 15;
            Ws[ml][kl] = W[(size_t)(m0 + ml) * K + k0 + kl];
        }
        __syncthreads();
        #pragma unroll
        for (int k = 0; k < BKK; k++) {
            float a[4], w[4];
            #pragma unroll
            for (int i = 0; i < 4; i++) a[i] = As[k][tx * 4 + i];
            #pragma unroll
            for (int j = 0; j < 4; j++) w[j] = Ws[ty * 4 + j][k];
            #pragma unroll
            for (int j = 0; j < 4; j++)
                #pragma unroll
                for (int i = 0; i < 4; i++) acc[j][i] += w[j] * a[i];
        }
        __syncthreads();
    }
    #pragma unroll
    for (int j = 0; j < 4; j++) {
        int m = m0 + ty * 4 + j;
        float bs = bias ? bias[m] : 0.f;
        float* orow = out + (size_t)b * OC * P + (size_t)m * P + p0;
        #pragma unroll
        for (int i = 0; i < 4; i++) orow[tx * 4 + i] = acc[j][i] + bs;
    }
}

// ---------------- NT GEMM for patch-merge reduction ----------------
__global__ __launch_bounds__(256) void gemm_nt(
    const float* __restrict__ A,  // [B*P, K] row-major
    const float* __restrict__ W,  // [OC, K]
    float* __restrict__ out, int K, int P, int OC)
{
    int b  = blockIdx.z;
    int p0 = blockIdx.x * BN;
    int m0 = blockIdx.y * BM;
    const float* Ab = A + (size_t)b * P * K;
    __shared__ float As[BN][BKK + 1];
    __shared__ float Ws[BM][BKK + 1];
    int tid = threadIdx.x, tx = tid & 15, ty = tid >> 4;
    float acc[4][4] = {};
    for (int k0 = 0; k0 < K; k0 += BKK) {
        #pragma unroll
        for (int e = tid; e < BN * BKK; e += 256) {
            int pl = e >> 4, kl = e & 15;
            As[pl][kl] = Ab[(size_t)(p0 + pl) * K + k0 + kl];
        }
        #pragma unroll
        for (int e = tid; e < BM * BKK; e += 256) {
            int ml = e >> 4, kl = e & 15;
            Ws[ml][kl] = W[(size_t)(m0 + ml) * K + k0 + kl];
        }
        __syncthreads();
        #pragma unroll
        for (int k = 0; k < BKK; k++) {
            float a[4], w[4];
            #pragma unroll
            for (int i = 0; i < 4; i++) a[i] = As[tx * 4 + i][k];
            #pragma unroll
            for (int j = 0; j < 4; j++) w[j] = Ws[ty * 4 + j][k];
            #pragma unroll
            for (int j = 0; j < 4; j++)
                #pragma unroll
                for (int i = 0; i < 4; i++) acc[j][i] += w[j] * a[i];
        }
        __syncthreads();
    }
    #pragma unroll
    for (int j = 0; j < 4; j++) {
        int m = m0 + ty * 4 + j;
        float* orow = out + (size_t)b * OC * P + (size_t)m * P + p0;
        #pragma unroll
        for (int i = 0; i < 4; i++) orow[tx * 4 + i] = acc[j][i];
    }
}

// ---------------- local windowed attention (8x8 windows, 64 tokens, d=32) ----------------
__global__ __launch_bounds__(64) void local_attn(
    const float* __restrict__ qkv,  // [B, 768, 4096]
    float* __restrict__ gx)         // [B, 256, 4096]
{
    int win  = blockIdx.x;
    int gxc  = win & 7;
    int gy   = (win >> 3) & 7;
    int head = (win >> 6) & 7;
    int b    = win >> 9;
    int tid  = threadIdx.x;

    __shared__ float Ks[64 * 36];
    __shared__ float Vs[64 * 36];
    const float* base = qkv + (size_t)b * 768 * HWSZ;
    int qc = head * 32, kc = 256 + head * 32, vc = 512 + head * 32;

    for (int i = 0; i < 32; i++) {
        int d = i, t = tid;
        int pix = (gy * 8 + (t >> 3)) * 64 + gxc * 8 + (t & 7);
        Ks[t * 36 + d] = base[(size_t)(kc + d) * HWSZ + pix];
        Vs[t * 36 + d] = base[(size_t)(vc + d) * HWSZ + pix];
    }
    int mypix = (gy * 8 + (tid >> 3)) * 64 + gxc * 8 + (tid & 7);
    float q[32];
    #pragma unroll
    for (int d = 0; d < 32; d++) q[d] = base[(size_t)(qc + d) * HWSZ + mypix] * SCALE;
    __syncthreads();

    float mmax = -1e30f, l = 0.f, o[32] = {};
    for (int j = 0; j < 64; j++) {
        float s = 0.f;
        #pragma unroll
        for (int d = 0; d < 32; d++) s += q[d] * Ks[j * 36 + d];
        float mn = fmaxf(mmax, s);
        float corr = __expf(mmax - mn);
        float pj = __expf(s - mn);
        l = l * corr + pj;
        #pragma unroll
        for (int d = 0; d < 32; d++) o[d] = o[d] * corr + pj * Vs[j * 36 + d];
        mmax = mn;
    }
    float inv = 1.f / l;
    float* gout = gx + (size_t)b * CDIM * HWSZ;
    #pragma unroll
    for (int d = 0; d < 32; d++)
        gout[(size_t)(head * 32 + d) * HWSZ + mypix] = o[d] * inv;
}

// ---------------- patch-merge layernorm: one block per pooled pixel ----------------
__global__ __launch_bounds__(256) void patch_merge_ln(
    const float* __restrict__ gxn,   // grid_x [B,256,4096]
    const float* __restrict__ lnw, const float* __restrict__ lnb,
    float* __restrict__ mn)          // [B*1024, 1024]
{
    int pix = blockIdx.x;
    int b = pix >> 10, op = pix & 1023;
    int oh = op >> 5, ow = op & 31;
    int t = threadIdx.x;
    const float* base = gxn + (size_t)b * CDIM * HWSZ;
    float v[4];
    #pragma unroll
    for (int i = 0; i < 4; i++) {
        int h = 2 * oh + (i & 1);
        int w = 2 * ow + (i >> 1);
        v[i] = base[(size_t)t * HWSZ + h * 64 + w];
    }
    float s  = v[0] + v[1] + v[2] + v[3];
    float s2 = v[0]*v[0] + v[1]*v[1] + v[2]*v[2] + v[3]*v[3];
    __shared__ float ls[256], ls2[256];
    ls[t] = s; ls2[t] = s2; __syncthreads();
    for (int off = 128; off > 0; off >>= 1) {
        if (t < off) { ls[t] += ls[t + off]; ls2[t] += ls2[t + off]; }
        __syncthreads();
    }
    float mu  = ls[0] * (1.f / 1024.f);
    float var = ls2[0] * (1.f / 1024.f) - mu * mu;
    float r = rsqrtf(var + EPS_LN);
    float* orow = mn + (size_t)pix * 1024;
    #pragma unroll
    for (int i = 0; i < 4; i++) {
        int j = i * 256 + t;
        orow[j] = (v[i] - mu) * r * lnw[j] + lnb[j];
    }
}

// ---------------- transpose + cast: fp32 [B,Csrc,P] (32-ch slab per head) -> bf16 [B*8, P, 32]
__global__ __launch_bounds__(256) void transpose_cast(
    const float* __restrict__ src, unsigned short* __restrict__ dst,
    int Csrc, int coff, int P, float scale)
{
    int b = blockIdx.z, h = blockIdx.y, p0 = blockIdx.x * 64;
    __shared__ float ld[32][65];
    int t = threadIdx.x;
    {
        int d = t >> 3, pb = (t & 7) * 8;
        const float* s = src + ((size_t)b * Csrc + coff + h * 32 + d) * P + p0 + pb;
        float4 v0 = *(const float4*)s;
        float4 v1 = *(const float4*)(s + 4);
        ld[d][pb + 0] = v0.x; ld[d][pb + 1] = v0.y; ld[d][pb + 2] = v0.z; ld[d][pb + 3] = v0.w;
        ld[d][pb + 4] = v1.x; ld[d][pb + 5] = v1.y; ld[d][pb + 6] = v1.z; ld[d][pb + 7] = v1.w;
    }
    __syncthreads();
    {
        int q = t >> 2, slot = t & 3;
        unsigned int u[4];
        #pragma unroll
        for (int wds = 0; wds < 4; wds++) {
            unsigned short lo = f2bf(ld[slot * 8 + wds * 2][q] * scale);
            unsigned short hi = f2bf(ld[slot * 8 + wds * 2 + 1][q] * scale);
            u[wds] = (unsigned int)lo | ((unsigned int)hi << 16);
        }
        unsigned short* dp = dst + ((size_t)(b * 8 + h) * P + p0 + q) * 32 + slot * 8;
        *(uint4*)dp = make_uint4(u[0], u[1], u[2], u[3]);
    }
}

// ---------------- elementwise cast: V half of kv fp32 [B,512,1024] -> bf16 [B*8,32,1024]
__global__ __launch_bounds__(256) void cast_v_bf16(
    const float* __restrict__ kv, unsigned short* __restrict__ vT)
{
    int i = blockIdx.x * 256 + threadIdx.x;     // 262144 float4-groups total
    int b = i >> 16, r4 = i & 65535;
    const float4 v = *(const float4*)(kv + (size_t)b * 524288 + 262144 + (size_t)r4 * 4);
    unsigned int u0 = (unsigned int)f2bf(v.x) | ((unsigned int)f2bf(v.y) << 16);
    unsigned int u1 = (unsigned int)f2bf(v.z) | ((unsigned int)f2bf(v.w) << 16);
    *(uint2*)(vT + (size_t)b * 262144 + (size_t)r4 * 4) = make_uint2(u0, u1);
}

// ---------------- global attention, bf16 MFMA flash ----------------
// qT: [B*8, 4096, 32] bf16 (scale folded); kT: [B*8, 1024, 32]; vT: [B*8, 32, 1024]
// go: [B, 4096, 256] fp32
__global__ __launch_bounds__(256) void global_attn_mfma(
    const unsigned short* __restrict__ qT,
    const unsigned short* __restrict__ kT,
    const unsigned short* __restrict__ vT,
    float* __restrict__ go)
{
    int blk = blockIdx.x;
    int qt = blk & 63, h = (blk >> 6) & 7, b = blk >> 9;
    int bh = b * 8 + h;
    int w = threadIdx.x >> 6, lane = threadIdx.x & 63;
    int m = lane & 15, g = lane >> 4;
    int qbase = qt * 64 + w * 16;

    __shared__ __align__(16) unsigned char plds[4][2048];  // per-wave P tile [16q][64k] bf16 (slot-swizzled)
    unsigned char* pl = plds[w];

    // Q as B-operand of S^T = K·Q^T: lane holds col q=m, k-dim d = g*8+e
    v8s qf = *(const v8s*)(qT + ((size_t)bh * 4096 + qbase + m) * 32 + g * 8);

    v4f o0 = {0.f, 0.f, 0.f, 0.f}, o1 = {0.f, 0.f, 0.f, 0.f};
    float m_run = -1e30f, l_run = 0.f;
    const v4f zf = {0.f, 0.f, 0.f, 0.f};

    #pragma unroll 1
    for (int t = 0; t < 16; t++) {
        int k0 = t * 64;
        const unsigned short* kp = kT + ((size_t)bh * 1024 + k0 + m) * 32 + g * 8;
        v8s ka0 = *(const v8s*)(kp);
        v8s ka1 = *(const v8s*)(kp + 16 * 32);
        v8s ka2 = *(const v8s*)(kp + 32 * 32);
        v8s ka3 = *(const v8s*)(kp + 48 * 32);
        // S^T tiles: D[16key x 16q], lane: col q=m, row key = kt*16 + g*4 + r
        v4f s0 = __builtin_amdgcn_mfma_f32_16x16x32_bf16(ka0, qf, zf, 0, 0, 0);
        v4f s1 = __builtin_amdgcn_mfma_f32_16x16x32_bf16(ka1, qf, zf, 0, 0, 0);
        v4f s2 = __builtin_amdgcn_mfma_f32_16x16x32_bf16(ka2, qf, zf, 0, 0, 0);
        v4f s3 = __builtin_amdgcn_mfma_f32_16x16x32_bf16(ka3, qf, zf, 0, 0, 0);

        // tile max for this lane's 16 scores (all belong to query q=m)
        float p0m = fmaxf(fmaxf(s0[0], s0[1]), fmaxf(s0[2], s0[3]));
        float p1m = fmaxf(fmaxf(s1[0], s1[1]), fmaxf(s1[2], s1[3]));
        float p2m = fmaxf(fmaxf(s2[0], s2[1]), fmaxf(s2[2], s2[3]));
        float p3m = fmaxf(fmaxf(s3[0], s3[1]), fmaxf(s3[2], s3[3]));
        float pmax = fmaxf(fmaxf(p0m, p1m), fmaxf(p2m, p3m));
        pmax = fmaxf(pmax, __shfl_xor(pmax, 16));
        pmax = fmaxf(pmax, __shfl_xor(pmax, 32));

        float m_new = fmaxf(m_run, pmax);
        float corr = __expf(m_run - m_new);
        m_run = m_new;

        float p[16];
        float lsum = 0.f;
        #pragma unroll
        for (int r = 0; r < 4; r++) { p[r]      = __expf(s0[r] - m_new); lsum += p[r]; }
        #pragma unroll
        for (int r = 0; r < 4; r++) { p[4 + r]  = __expf(s1[r] - m_new); lsum += p[4 + r]; }
        #pragma unroll
        for (int r = 0; r < 4; r++) { p[8 + r]  = __expf(s2[r] - m_new); lsum += p[8 + r]; }
        #pragma unroll
        for (int r = 0; r < 4; r++) { p[12 + r] = __expf(s3[r] - m_new); lsum += p[12 + r]; }
        l_run = l_run * corr + lsum;

        // rescale O (rows q = g*4+r) with corr of those queries
        float corrq[4];
        #pragma unroll
        for (int r = 0; r < 4; r++) corrq[r] = __shfl(corr, g * 4 + r);
        #pragma unroll
        for (int r = 0; r < 4; r++) { o0[r] *= corrq[r]; o1[r] *= corrq[r]; }

        // pack P (bf16) into per-wave LDS tile [q=m][key], slot-swizzled
        #pragma unroll
        for (int kt = 0; kt < 4; kt++) {
            int slot = kt * 2 + (g >> 1);
            unsigned char* bp = pl + m * 128 + ((slot ^ (m & 7)) << 4) + (g & 1) * 8;
            unsigned int u01 = (unsigned int)f2bf(p[kt * 4 + 0]) | ((unsigned int)f2bf(p[kt * 4 + 1]) << 16);
            unsigned int u23 = (unsigned int)f2bf(p[kt * 4 + 2]) | ((unsigned int)f2bf(p[kt * 4 + 3]) << 16);
            *(unsigned int*)(bp)     = u01;
            *(unsigned int*)(bp + 4) = u23;
        }
        __syncthreads();

        // PV: O[16q x 16d] += P[16q x 32k] * V[32k x 16d], two k-chunks, two d-tiles
        #pragma unroll
        for (int c = 0; c < 2; c++) {
            v8s pa = *(const v8s*)(pl + m * 128 + (((c * 4 + g) ^ (m & 7)) << 4));
            const unsigned short* vp = vT + ((size_t)bh * 32 + m) * 1024 + k0 + c * 32 + g * 8;
            v8s vb0 = *(const v8s*)(vp);
            v8s vb1 = *(const v8s*)(vp + 16 * 1024);
            o0 = __builtin_amdgcn_mfma_f32_16x16x32_bf16(pa, vb0, o0, 0, 0, 0);
            o1 = __builtin_amdgcn_mfma_f32_16x16x32_bf16(pa, vb1, o1, 0, 0, 0);
        }
        __syncthreads();
    }

    float lf = l_run;
    lf += __shfl_xor(lf, 16);
    lf += __shfl_xor(lf, 32);
    float inv = 1.f / lf;
    float invq[4];
    #pragma unroll
    for (int r = 0; r < 4; r++) invq[r] = __shfl(inv, g * 4 + r);

    #pragma unroll
    for (int r = 0; r < 4; r++) {
        size_t row = ((size_t)b * 4096 + qbase + g * 4 + r) * 256 + h * 32;
        go[row + m]      = o0[r] * invq[r];
        go[row + 16 + m] = o1[r] * invq[r];
    }
}

// ---------------- launcher ----------------
extern "C" void kernel_launch(void* const* d_in, const int* in_sizes, int n_in,
                              void* d_out, int out_size, void* d_ws, size_t ws_size,
                              hipStream_t stream)
{
    const float* x           = (const float*)d_in[0];
    const float* norm_w      = (const float*)d_in[1];
    const float* norm_b      = (const float*)d_in[2];
    const float* qkv_w       = (const float*)d_in[3];
    const float* qkv_b       = (const float*)d_in[4];
    const float* proj_w      = (const float*)d_in[5];
    const float* proj_b      = (const float*)d_in[6];
    const float* grid_norm_w = (const float*)d_in[7];
    const float* grid_norm_b = (const float*)d_in[8];
    const float* pm_ln_w     = (const float*)d_in[9];
    const float* pm_ln_b     = (const float*)d_in[10];
    const float* pm_red_w    = (const float*)d_in[11];
    const float* ds_norm_w   = (const float*)d_in[12];
    const float* ds_norm_b   = (const float*)d_in[13];
    const float* q_w         = (const float*)d_in[14];
    const float* q_b         = (const float*)d_in[15];
    const float* kv_w        = (const float*)d_in[16];
    const float* kv_b        = (const float*)d_in[17];
    float* out = (float*)d_out;

    float* wsf = (float*)d_ws;
    // region 0 (12.58M floats): qkv, later mn, later qT/kT/vT + qg + go
    float* qkvbuf = wsf;                       // [4,768,4096]
    float* mnbuf  = wsf;                       // [4096,1024]  (qkv dead)
    unsigned short* qTu = (unsigned short*)(wsf);             // [32,4096,32] bf16 (mn dead)
    unsigned short* kTu = (unsigned short*)(wsf + 2097152);   // [32,1024,32] bf16
    unsigned short* vTu = (unsigned short*)(wsf + 2621440);   // [32,32,1024] bf16
    float* qgbuf  = wsf + 4194304;             // [4,256,4096]
    float* gobuf  = wsf + 8388608;             // [4,4096,256]  (p-major!)
    // region 1: gx, later pm + kv
    float* gxbuf  = wsf + 12582912;            // [4,256,4096]
    float* pmbuf  = wsf + 12582912;            // [4,256,1024] (gx dead)
    float* kvbuf  = wsf + 12582912 + 1048576;  // [4,512,1024]
    // region 2: grid_x (live to the end)
    float* gridx  = wsf + 16777216;            // [4,256,4096]
    // small scratch
    float* part   = wsf + 20971520;
    float* stats0 = part + 512;
    float* stats1 = stats0 + 8;
    float* stats2 = stats1 + 8;

    // 1. stats of x
    gn_partial<<<BATCH * 64, 256, 0, stream>>>(x, nullptr, 1048576, 64, part);
    gn_finalize<<<1, 64, 0, stream>>>(part, 64, 1.f / 1048576.f, EPS_GN, stats0, BATCH);
    // 2. qkv conv (norm folded)
    gemm_conv<false><<<dim3(64, 12, BATCH), 256, 0, stream>>>(
        x, nullptr, qkv_w, qkv_b, qkvbuf, 256, 4096, 768, stats0, norm_w, norm_b);
    // 3. local windowed attention
    local_attn<<<2048, 64, 0, stream>>>(qkvbuf, gxbuf);
    // 4. stats of x+gx
    gn_partial<<<BATCH * 64, 256, 0, stream>>>(x, gxbuf, 1048576, 64, part);
    gn_finalize<<<1, 64, 0, stream>>>(part, 64, 1.f / 1048576.f, EPS_GN, stats1, BATCH);
    // 5. grid_x = GN(x+gx)
    add_norm<<<16384, 256, 0, stream>>>(x, gxbuf, stats1, grid_norm_w, grid_norm_b, gridx);
    // 6. patch-merge layernorm rows
    patch_merge_ln<<<4096, 256, 0, stream>>>(gridx, pm_ln_w, pm_ln_b, mnbuf);
    // 7. patch-merge reduction GEMM
    gemm_nt<<<dim3(16, 4, BATCH), 256, 0, stream>>>(mnbuf, pm_red_w, pmbuf, 1024, 1024, 256);
    // 8. stats of pm
    gn_partial<<<BATCH * 16, 256, 0, stream>>>(pmbuf, nullptr, 262144, 16, part);
    gn_finalize<<<1, 64, 0, stream>>>(part, 16, 1.f / 262144.f, EPS_GN, stats2, BATCH);
    // 9. kv conv (ds-norm folded)
    gemm_conv<false><<<dim3(16, 8, BATCH), 256, 0, stream>>>(
        pmbuf, nullptr, kv_w, kv_b, kvbuf, 256, 1024, 512, stats2, ds_norm_w, ds_norm_b);
    // 9b. kT / vT bf16 layouts
    transpose_cast<<<dim3(16, 8, BATCH), 256, 0, stream>>>(kvbuf, kTu, 512, 0, 1024, 1.0f);
    cast_v_bf16<<<1024, 256, 0, stream>>>(kvbuf, vTu);
    // 10. q conv on grid_x
    gemm_conv<false><<<dim3(64, 4, BATCH), 256, 0, stream>>>(
        gridx, nullptr, q_w, q_b, qgbuf, 256, 4096, 256, nullptr, nullptr, nullptr);
    // 10b. qT bf16 layout (scale folded)
    transpose_cast<<<dim3(64, 8, BATCH), 256, 0, stream>>>(qgbuf, qTu, 256, 0, 4096, SCALE);
    // 11. global attention (MFMA) -> go (p-major)
    global_attn_mfma<<<2048, 256, 0, stream>>>(qTu, kTu, vTu, gobuf);
    // 12. proj conv on (go^T + grid_x) -> out
    gemm_conv<true><<<dim3(64, 4, BATCH), 256, 0, stream>>>(
        gobuf, gridx, proj_w, proj_b, out, 256, 4096, 256, nullptr, nullptr, nullptr);
}

// Round 4
// 330.625 us; speedup vs baseline: 3.5278x; 2.0572x over previous
//
#include <hip/hip_runtime.h>
#include <hip/hip_bf16.h>

// Problem constants
#define BATCH 4
#define CDIM 256
#define HWSZ 4096          // 64*64
#define P2 1024            // 32*32 pooled pixels per batch
#define SCALE 0.17677669529663687f
#define EPS_GN 1e-6f
#define EPS_LN 1e-5f

typedef short v8s __attribute__((ext_vector_type(8)));
typedef float v4f __attribute__((ext_vector_type(4)));

__device__ __forceinline__ unsigned short f2bf(float f) {
    __hip_bfloat16 h = __float2bfloat16(f);
    return *reinterpret_cast<unsigned short*>(&h);
}
__device__ __forceinline__ float bf2f(unsigned short u) {
    return __uint_as_float(((unsigned int)u) << 16);
}
__device__ __forceinline__ void async16(void* lds, const void* g) {
    __builtin_amdgcn_global_load_lds(
        (const __attribute__((address_space(1))) unsigned int*)g,
        (__attribute__((address_space(3))) unsigned int*)lds, 16, 0, 0);
}

// ---------------- GroupNorm stats (two-stage, deterministic) ----------------
__global__ void gn_partial(const float* __restrict__ a, const float* __restrict__ a2,
                           int per_batch, int nblk, float* __restrict__ part)
{
    int bb  = blockIdx.x / nblk;
    int blk = blockIdx.x % nblk;
    const float* pa  = a  + (size_t)bb * per_batch;
    const float* pa2 = a2 ? a2 + (size_t)bb * per_batch : nullptr;
    int tid = threadIdx.x;
    float s = 0.f, s2 = 0.f;
    for (int i = blk * 256 + tid; i < per_batch; i += nblk * 256) {
        float v = pa[i];
        if (pa2) v += pa2[i];
        s += v; s2 += v * v;
    }
    __shared__ float ls[256], ls2[256];
    ls[tid] = s; ls2[tid] = s2; __syncthreads();
    for (int off = 128; off > 0; off >>= 1) {
        if (tid < off) { ls[tid] += ls[tid + off]; ls2[tid] += ls2[tid + off]; }
        __syncthreads();
    }
    if (tid == 0) {
        part[blockIdx.x * 2]     = ls[0];
        part[blockIdx.x * 2 + 1] = ls2[0];
    }
}

__global__ void gn_finalize(const float* __restrict__ part, int nblk, float inv_n,
                            float eps, float* __restrict__ stats, int nb)
{
    int b = threadIdx.x;
    if (b < nb) {
        float s = 0.f, s2 = 0.f;
        for (int i = 0; i < nblk; i++) {
            s  += part[(b * nblk + i) * 2];
            s2 += part[(b * nblk + i) * 2 + 1];
        }
        float m = s * inv_n;
        float v = s2 * inv_n - m * m;
        stats[b * 2]     = m;
        stats[b * 2 + 1] = rsqrtf(v + eps);
    }
}

// ---------------- weight cast fp32 -> bf16 (all 5 weight matrices) ----------------
__global__ void cast_weights(const float* __restrict__ w0, const float* __restrict__ w1,
                             const float* __restrict__ w2, const float* __restrict__ w3,
                             const float* __restrict__ w4, unsigned short* __restrict__ dst)
{
    int i = blockIdx.x * 256 + threadIdx.x;    // 180224 threads, 4 elems each
    int idx = i * 4;
    const float* src; int off;
    if      (idx < 196608) { src = w0; off = 0; }
    else if (idx < 458752) { src = w1; off = 196608; }
    else if (idx < 589824) { src = w2; off = 458752; }
    else if (idx < 655360) { src = w3; off = 589824; }
    else                   { src = w4; off = 655360; }
    float4 v = *(const float4*)(src + idx - off);
    unsigned int u0 = (unsigned int)f2bf(v.x) | ((unsigned int)f2bf(v.y) << 16);
    unsigned int u1 = (unsigned int)f2bf(v.z) | ((unsigned int)f2bf(v.w) << 16);
    *(uint2*)(dst + idx) = make_uint2(u0, u1);
}

// ---------------- transpose + (optional add) + (optional norm) + cast ----------------
// A (and A2): [b][256][P] fp32 c-major.  dst: [b][P][256] bf16 p-major.
__global__ __launch_bounds__(256) void tnc(
    const float* __restrict__ A, const float* __restrict__ A2,
    const float* __restrict__ stats, const float* __restrict__ nw,
    const float* __restrict__ nb, unsigned short* __restrict__ dst, int P)
{
    int b = blockIdx.z, c0 = blockIdx.y * 64, p0 = blockIdx.x * 64;
    __shared__ float ld[64][65];
    int t = threadIdx.x;
    {
        int ch = t >> 2, pq = (t & 3) * 16;
        size_t base = ((size_t)b * 256 + c0 + ch) * P + p0 + pq;
        float4 f0 = *(const float4*)(A + base);
        float4 f1 = *(const float4*)(A + base + 4);
        float4 f2 = *(const float4*)(A + base + 8);
        float4 f3 = *(const float4*)(A + base + 12);
        if (A2) {
            float4 g0 = *(const float4*)(A2 + base);
            float4 g1 = *(const float4*)(A2 + base + 4);
            float4 g2 = *(const float4*)(A2 + base + 8);
            float4 g3 = *(const float4*)(A2 + base + 12);
            f0.x += g0.x; f0.y += g0.y; f0.z += g0.z; f0.w += g0.w;
            f1.x += g1.x; f1.y += g1.y; f1.z += g1.z; f1.w += g1.w;
            f2.x += g2.x; f2.y += g2.y; f2.z += g2.z; f2.w += g2.w;
            f3.x += g3.x; f3.y += g3.y; f3.z += g3.z; f3.w += g3.w;
        }
        float sw = 1.f, sb = 0.f;
        if (stats) {
            float mean = stats[b * 2], r = stats[b * 2 + 1];
            float wv = nw[c0 + ch];
            sw = r * wv; sb = nb[c0 + ch] - mean * r * wv;
        }
        ld[ch][pq + 0]  = f0.x * sw + sb; ld[ch][pq + 1]  = f0.y * sw + sb;
        ld[ch][pq + 2]  = f0.z * sw + sb; ld[ch][pq + 3]  = f0.w * sw + sb;
        ld[ch][pq + 4]  = f1.x * sw + sb; ld[ch][pq + 5]  = f1.y * sw + sb;
        ld[ch][pq + 6]  = f1.z * sw + sb; ld[ch][pq + 7]  = f1.w * sw + sb;
        ld[ch][pq + 8]  = f2.x * sw + sb; ld[ch][pq + 9]  = f2.y * sw + sb;
        ld[ch][pq + 10] = f2.z * sw + sb; ld[ch][pq + 11] = f2.w * sw + sb;
        ld[ch][pq + 12] = f3.x * sw + sb; ld[ch][pq + 13] = f3.y * sw + sb;
        ld[ch][pq + 14] = f3.z * sw + sb; ld[ch][pq + 15] = f3.w * sw + sb;
    }
    __syncthreads();
    {
        int p = t >> 2, cb = (t & 3) * 16;
        unsigned int u[8];
        #pragma unroll
        for (int j = 0; j < 8; j++) {
            unsigned short lo = f2bf(ld[cb + 2 * j][p]);
            unsigned short hi = f2bf(ld[cb + 2 * j + 1][p]);
            u[j] = (unsigned int)lo | ((unsigned int)hi << 16);
        }
        unsigned short* dp = dst + ((size_t)b * P + p0 + p) * 256 + c0 + cb;
        *(uint4*)(dp)     = make_uint4(u[0], u[1], u[2], u[3]);
        *(uint4*)(dp + 8) = make_uint4(u[4], u[5], u[6], u[7]);
    }
}

// ---------------- MFMA GEMM: OUT[b][m][p] = sum_k actT[b][p][k]*W[m][k] + bias ----------
// actT bf16 [B][P][K], W bf16 [OC][K], OUT fp32 [B][OC][P].
__global__ __launch_bounds__(256) void gemm_bf16(
    const unsigned short* __restrict__ actT,
    const unsigned short* __restrict__ Wb,
    const float* __restrict__ bias,
    float* __restrict__ out, int K, int P, int OC)
{
    int b  = blockIdx.z;
    int p0 = blockIdx.x * 128;
    int m0 = blockIdx.y * 64;
    int tid = threadIdx.x;
    int w = tid >> 6, lane = tid & 63;
    int lm = lane & 15, lg = lane >> 4;
    int wm = w >> 1, wp = w & 1;
    int l8 = lane >> 3, cc = lane & 7;

    __shared__ __align__(16) unsigned short Wt[64 * 64];    // [m][64k], 128B rows, swizzled
    __shared__ __align__(16) unsigned short At[128 * 64];   // [p][64k], 128B rows, swizzled

    const unsigned short* actB = actT + (size_t)b * P * K;

    v4f acc[2][4];
    #pragma unroll
    for (int i = 0; i < 2; i++)
        #pragma unroll
        for (int j = 0; j < 4; j++) acc[i][j] = (v4f){0.f, 0.f, 0.f, 0.f};

    for (int ks = 0; ks < K; ks += 64) {
        // stage W tile: 8KB = 2 x 1KB per wave
        #pragma unroll
        for (int i = 0; i < 2; i++) {
            int ml = w * 16 + i * 8 + l8;
            int g = cc ^ (ml & 7);
            async16(&Wt[(w * 16 + i * 8) * 64], Wb + (size_t)(m0 + ml) * K + ks + g * 8);
        }
        // stage act tile: 16KB = 4 x 1KB per wave
        #pragma unroll
        for (int i = 0; i < 4; i++) {
            int pl = w * 32 + i * 8 + l8;
            int g = cc ^ (pl & 7);
            async16(&At[(w * 32 + i * 8) * 64], actB + (size_t)(p0 + pl) * K + ks + g * 8);
        }
        __syncthreads();
        #pragma unroll
        for (int kk = 0; kk < 2; kk++) {
            v8s af[2], bfv[4];
            #pragma unroll
            for (int mt = 0; mt < 2; mt++) {
                int m = wm * 32 + mt * 16 + lm;
                int ch = (kk * 4 + lg) ^ (m & 7);
                af[mt] = *(const v8s*)&Wt[m * 64 + ch * 8];
            }
            #pragma unroll
            for (int pt = 0; pt < 4; pt++) {
                int p = wp * 64 + pt * 16 + lm;
                int ch = (kk * 4 + lg) ^ (p & 7);
                bfv[pt] = *(const v8s*)&At[p * 64 + ch * 8];
            }
            #pragma unroll
            for (int mt = 0; mt < 2; mt++)
                #pragma unroll
                for (int pt = 0; pt < 4; pt++)
                    acc[mt][pt] = __builtin_amdgcn_mfma_f32_16x16x32_bf16(
                        af[mt], bfv[pt], acc[mt][pt], 0, 0, 0);
        }
        __syncthreads();
    }
    // epilogue: D row = lg*4+r, col = lm
    #pragma unroll
    for (int mt = 0; mt < 2; mt++) {
        #pragma unroll
        for (int r = 0; r < 4; r++) {
            int m = m0 + wm * 32 + mt * 16 + lg * 4 + r;
            float bs = bias ? bias[m] : 0.f;
            float* orow = out + (size_t)b * OC * P + (size_t)m * P + p0 + wp * 64;
            #pragma unroll
            for (int pt = 0; pt < 4; pt++)
                orow[pt * 16 + lm] = acc[mt][pt][r] + bs;
        }
    }
}

// ---------------- local windowed attention (8x8 windows, 64 tokens, d=32) ----------------
__global__ __launch_bounds__(64) void local_attn(
    const float* __restrict__ qkv,  // [B, 768, 4096]
    float* __restrict__ gx)         // [B, 256, 4096]
{
    int win  = blockIdx.x;
    int gxc  = win & 7;
    int gy   = (win >> 3) & 7;
    int head = (win >> 6) & 7;
    int b    = win >> 9;
    int tid  = threadIdx.x;

    __shared__ float Ks[64 * 36];
    __shared__ float Vs[64 * 36];
    const float* base = qkv + (size_t)b * 768 * HWSZ;
    int qc = head * 32, kc = 256 + head * 32, vc = 512 + head * 32;

    for (int i = 0; i < 32; i++) {
        int d = i, t = tid;
        int pix = (gy * 8 + (t >> 3)) * 64 + gxc * 8 + (t & 7);
        Ks[t * 36 + d] = base[(size_t)(kc + d) * HWSZ + pix];
        Vs[t * 36 + d] = base[(size_t)(vc + d) * HWSZ + pix];
    }
    int mypix = (gy * 8 + (tid >> 3)) * 64 + gxc * 8 + (tid & 7);
    float q[32];
    #pragma unroll
    for (int d = 0; d < 32; d++) q[d] = base[(size_t)(qc + d) * HWSZ + mypix] * SCALE;
    __syncthreads();

    float mmax = -1e30f, l = 0.f, o[32] = {};
    for (int j = 0; j < 64; j++) {
        float s = 0.f;
        #pragma unroll
        for (int d = 0; d < 32; d++) s += q[d] * Ks[j * 36 + d];
        float mn = fmaxf(mmax, s);
        float corr = __expf(mmax - mn);
        float pj = __expf(s - mn);
        l = l * corr + pj;
        #pragma unroll
        for (int d = 0; d < 32; d++) o[d] = o[d] * corr + pj * Vs[j * 36 + d];
        mmax = mn;
    }
    float inv = 1.f / l;
    float* gout = gx + (size_t)b * CDIM * HWSZ;
    #pragma unroll
    for (int d = 0; d < 32; d++)
        gout[(size_t)(head * 32 + d) * HWSZ + mypix] = o[d] * inv;
}

// ---------------- patch-merge layernorm (reads coalesced gxT, writes bf16 mn) ----------
__global__ __launch_bounds__(256) void patch_merge_ln2(
    const unsigned short* __restrict__ gxT,   // [B][4096][256] bf16
    const float* __restrict__ lnw, const float* __restrict__ lnb,
    unsigned short* __restrict__ mn)          // [B*1024][1024] bf16
{
    int pix = blockIdx.x;
    int b = pix >> 10, op = pix & 1023;
    int oh = op >> 5, ow = op & 31;
    int t = threadIdx.x;
    const unsigned short* base = gxT + (size_t)b * 4096 * 256;
    float v[4];
    #pragma unroll
    for (int i = 0; i < 4; i++) {
        int h = 2 * oh + (i & 1);
        int w = 2 * ow + (i >> 1);
        v[i] = bf2f(base[(size_t)(h * 64 + w) * 256 + t]);
    }
    float s  = v[0] + v[1] + v[2] + v[3];
    float s2 = v[0]*v[0] + v[1]*v[1] + v[2]*v[2] + v[3]*v[3];
    __shared__ float ls[256], ls2[256];
    ls[t] = s; ls2[t] = s2; __syncthreads();
    for (int off = 128; off > 0; off >>= 1) {
        if (t < off) { ls[t] += ls[t + off]; ls2[t] += ls2[t + off]; }
        __syncthreads();
    }
    float mu  = ls[0] * (1.f / 1024.f);
    float var = ls2[0] * (1.f / 1024.f) - mu * mu;
    float r = rsqrtf(var + EPS_LN);
    unsigned short* orow = mn + (size_t)pix * 1024;
    #pragma unroll
    for (int i = 0; i < 4; i++) {
        int j = i * 256 + t;
        orow[j] = f2bf((v[i] - mu) * r * lnw[j] + lnb[j]);
    }
}

// ---------------- transpose + cast: fp32 [B,Csrc,P] (32-ch slab per head) -> bf16 [B*8, P, 32]
__global__ __launch_bounds__(256) void transpose_cast(
    const float* __restrict__ src, unsigned short* __restrict__ dst,
    int Csrc, int coff, int P, float scale)
{
    int b = blockIdx.z, h = blockIdx.y, p0 = blockIdx.x * 64;
    __shared__ float ld[32][65];
    int t = threadIdx.x;
    {
        int d = t >> 3, pb = (t & 7) * 8;
        const float* s = src + ((size_t)b * Csrc + coff + h * 32 + d) * P + p0 + pb;
        float4 v0 = *(const float4*)s;
        float4 v1 = *(const float4*)(s + 4);
        ld[d][pb + 0] = v0.x; ld[d][pb + 1] = v0.y; ld[d][pb + 2] = v0.z; ld[d][pb + 3] = v0.w;
        ld[d][pb + 4] = v1.x; ld[d][pb + 5] = v1.y; ld[d][pb + 6] = v1.z; ld[d][pb + 7] = v1.w;
    }
    __syncthreads();
    {
        int q = t >> 2, slot = t & 3;
        unsigned int u[4];
        #pragma unroll
        for (int wds = 0; wds < 4; wds++) {
            unsigned short lo = f2bf(ld[slot * 8 + wds * 2][q] * scale);
            unsigned short hi = f2bf(ld[slot * 8 + wds * 2 + 1][q] * scale);
            u[wds] = (unsigned int)lo | ((unsigned int)hi << 16);
        }
        unsigned short* dp = dst + ((size_t)(b * 8 + h) * P + p0 + q) * 32 + slot * 8;
        *(uint4*)dp = make_uint4(u[0], u[1], u[2], u[3]);
    }
}

// ---------------- elementwise cast: V half of kv fp32 [B,512,1024] -> bf16 [B*8,32,1024]
__global__ __launch_bounds__(256) void cast_v_bf16(
    const float* __restrict__ kv, unsigned short* __restrict__ vT)
{
    int i = blockIdx.x * 256 + threadIdx.x;
    int b = i >> 16, r4 = i & 65535;
    const float4 v = *(const float4*)(kv + (size_t)b * 524288 + 262144 + (size_t)r4 * 4);
    unsigned int u0 = (unsigned int)f2bf(v.x) | ((unsigned int)f2bf(v.y) << 16);
    unsigned int u1 = (unsigned int)f2bf(v.z) | ((unsigned int)f2bf(v.w) << 16);
    *(uint2*)(vT + (size_t)b * 262144 + (size_t)r4 * 4) = make_uint2(u0, u1);
}

// ---------------- global attention, bf16 MFMA flash ----------------
__global__ __launch_bounds__(256) void global_attn_mfma(
    const unsigned short* __restrict__ qT,
    const unsigned short* __restrict__ kT,
    const unsigned short* __restrict__ vT,
    float* __restrict__ go)
{
    int blk = blockIdx.x;
    int qt = blk & 63, h = (blk >> 6) & 7, b = blk >> 9;
    int bh = b * 8 + h;
    int w = threadIdx.x >> 6, lane = threadIdx.x & 63;
    int m = lane & 15, g = lane >> 4;
    int qbase = qt * 64 + w * 16;

    __shared__ __align__(16) unsigned char plds[4][2048];
    unsigned char* pl = plds[w];

    v8s qf = *(const v8s*)(qT + ((size_t)bh * 4096 + qbase + m) * 32 + g * 8);

    v4f o0 = {0.f, 0.f, 0.f, 0.f}, o1 = {0.f, 0.f, 0.f, 0.f};
    float m_run = -1e30f, l_run = 0.f;
    const v4f zf = {0.f, 0.f, 0.f, 0.f};

    #pragma unroll 1
    for (int t = 0; t < 16; t++) {
        int k0 = t * 64;
        const unsigned short* kp = kT + ((size_t)bh * 1024 + k0 + m) * 32 + g * 8;
        v8s ka0 = *(const v8s*)(kp);
        v8s ka1 = *(const v8s*)(kp + 16 * 32);
        v8s ka2 = *(const v8s*)(kp + 32 * 32);
        v8s ka3 = *(const v8s*)(kp + 48 * 32);
        v4f s0 = __builtin_amdgcn_mfma_f32_16x16x32_bf16(ka0, qf, zf, 0, 0, 0);
        v4f s1 = __builtin_amdgcn_mfma_f32_16x16x32_bf16(ka1, qf, zf, 0, 0, 0);
        v4f s2 = __builtin_amdgcn_mfma_f32_16x16x32_bf16(ka2, qf, zf, 0, 0, 0);
        v4f s3 = __builtin_amdgcn_mfma_f32_16x16x32_bf16(ka3, qf, zf, 0, 0, 0);

        float p0m = fmaxf(fmaxf(s0[0], s0[1]), fmaxf(s0[2], s0[3]));
        float p1m = fmaxf(fmaxf(s1[0], s1[1]), fmaxf(s1[2], s1[3]));
        float p2m = fmaxf(fmaxf(s2[0], s2[1]), fmaxf(s2[2], s2[3]));
        float p3m = fmaxf(fmaxf(s3[0], s3[1]), fmaxf(s3[2], s3[3]));
        float pmax = fmaxf(fmaxf(p0m, p1m), fmaxf(p2m, p3m));
        pmax = fmaxf(pmax, __shfl_xor(pmax, 16));
        pmax = fmaxf(pmax, __shfl_xor(pmax, 32));

        float m_new = fmaxf(m_run, pmax);
        float corr = __expf(m_run - m_new);
        m_run = m_new;

        float p[16];
        float lsum = 0.f;
        #pragma unroll
        for (int r = 0; r < 4; r++) { p[r]      = __expf(s0[r] - m_new); lsum += p[r]; }
        #pragma unroll
        for (int r = 0; r < 4; r++) { p[4 + r]  = __expf(s1[r] - m_new); lsum += p[4 + r]; }
        #pragma unroll
        for (int r = 0; r < 4; r++) { p[8 + r]  = __expf(s2[r] - m_new); lsum += p[8 + r]; }
        #pragma unroll
        for (int r = 0; r < 4; r++) { p[12 + r] = __expf(s3[r] - m_new); lsum += p[12 + r]; }
        l_run = l_run * corr + lsum;

        float corrq[4];
        #pragma unroll
        for (int r = 0; r < 4; r++) corrq[r] = __shfl(corr, g * 4 + r);
        #pragma unroll
        for (int r = 0; r < 4; r++) { o0[r] *= corrq[r]; o1[r] *= corrq[r]; }

        #pragma unroll
        for (int kt = 0; kt < 4; kt++) {
            int slot = kt * 2 + (g >> 1);
            unsigned char* bp = pl + m * 128 + ((slot ^ (m & 7)) << 4) + (g & 1) * 8;
            unsigned int u01 = (unsigned int)f2bf(p[kt * 4 + 0]) | ((unsigned int)f2bf(p[kt * 4 + 1]) << 16);
            unsigned int u23 = (unsigned int)f2bf(p[kt * 4 + 2]) | ((unsigned int)f2bf(p[kt * 4 + 3]) << 16);
            *(unsigned int*)(bp)     = u01;
            *(unsigned int*)(bp + 4) = u23;
        }
        __syncthreads();

        #pragma unroll
        for (int c = 0; c < 2; c++) {
            v8s pa = *(const v8s*)(pl + m * 128 + (((c * 4 + g) ^ (m & 7)) << 4));
            const unsigned short* vp = vT + ((size_t)bh * 32 + m) * 1024 + k0 + c * 32 + g * 8;
            v8s vb0 = *(const v8s*)(vp);
            v8s vb1 = *(const v8s*)(vp + 16 * 1024);
            o0 = __builtin_amdgcn_mfma_f32_16x16x32_bf16(pa, vb0, o0, 0, 0, 0);
            o1 = __builtin_amdgcn_mfma_f32_16x16x32_bf16(pa, vb1, o1, 0, 0, 0);
        }
        __syncthreads();
    }

    float lf = l_run;
    lf += __shfl_xor(lf, 16);
    lf += __shfl_xor(lf, 32);
    float inv = 1.f / lf;
    float invq[4];
    #pragma unroll
    for (int r = 0; r < 4; r++) invq[r] = __shfl(inv, g * 4 + r);

    #pragma unroll
    for (int r = 0; r < 4; r++) {
        size_t row = ((size_t)b * 4096 + qbase + g * 4 + r) * 256 + h * 32;
        go[row + m]      = o0[r] * invq[r];
        go[row + 16 + m] = o1[r] * invq[r];
    }
}

// ---------------- proj input: projT[p][c] = bf16(gxT + go) ----------------
__global__ void proj_prep(const unsigned short* __restrict__ gxT,
                          const float* __restrict__ go,
                          unsigned short* __restrict__ projT)
{
    size_t i = ((size_t)blockIdx.x * 256 + threadIdx.x) * 4;
    uint2 gv = *(const uint2*)(gxT + i);
    float4 gof = *(const float4*)(go + i);
    float a0 = __uint_as_float(gv.x << 16) + gof.x;
    float a1 = __uint_as_float(gv.x & 0xffff0000u) + gof.y;
    float a2 = __uint_as_float(gv.y << 16) + gof.z;
    float a3 = __uint_as_float(gv.y & 0xffff0000u) + gof.w;
    unsigned int u0 = (unsigned int)f2bf(a0) | ((unsigned int)f2bf(a1) << 16);
    unsigned int u1 = (unsigned int)f2bf(a2) | ((unsigned int)f2bf(a3) << 16);
    *(uint2*)(projT + i) = make_uint2(u0, u1);
}

// ---------------- launcher ----------------
extern "C" void kernel_launch(void* const* d_in, const int* in_sizes, int n_in,
                              void* d_out, int out_size, void* d_ws, size_t ws_size,
                              hipStream_t stream)
{
    const float* x           = (const float*)d_in[0];
    const float* norm_w      = (const float*)d_in[1];
    const float* norm_b      = (const float*)d_in[2];
    const float* qkv_w       = (const float*)d_in[3];
    const float* qkv_b       = (const float*)d_in[4];
    const float* proj_w      = (const float*)d_in[5];
    const float* proj_b      = (const float*)d_in[6];
    const float* grid_norm_w = (const float*)d_in[7];
    const float* grid_norm_b = (const float*)d_in[8];
    const float* pm_ln_w     = (const float*)d_in[9];
    const float* pm_ln_b     = (const float*)d_in[10];
    const float* pm_red_w    = (const float*)d_in[11];
    const float* ds_norm_w   = (const float*)d_in[12];
    const float* ds_norm_b   = (const float*)d_in[13];
    const float* q_w         = (const float*)d_in[14];
    const float* q_b         = (const float*)d_in[15];
    const float* kv_w        = (const float*)d_in[16];
    const float* kv_b        = (const float*)d_in[17];
    float* out = (float*)d_out;

    float* wsf = (float*)d_ws;
    // region A [0, 12.58M floats): qkvbuf early; then repacked small buffers.
    // Float-slot accounting (bf16 buffers use elems/2 float-slots):
    //   qkvbuf [0, 12,582,912)                      fp32 [4][768][4096]     (dead after step 5)
    //   mnb    [0, 2,097,152)                       bf16 [4096][1024]       (live steps 8-9)
    //   kTu    [0,   524,288)                       bf16 [32][1024][32]     (live steps 13-16; mnb dead)
    //   vTu    [524,288, 1,048,576)                 bf16 [32][32][1024]     (live steps 13-16)
    //   pm     [2,097,152, 3,145,728)               fp32 [4][256][1024]
    //   pmT    [3,145,728, 3,670,016)               bf16 [4][1024][256]
    //   kvbuf  [3,670,016, 5,767,168)               fp32 [4][512][1024]
    //   qg     [6,291,456, 10,485,760)              fp32 [4][256][4096]
    //   qTu    [10,485,760, 12,582,912)             bf16 [32][4096][32]
    float* qkvbuf         = wsf;
    unsigned short* mnb   = (unsigned short*)(wsf);
    unsigned short* kTu   = (unsigned short*)(wsf);               // reuses dead mnb
    unsigned short* vTu   = (unsigned short*)(wsf + 524288);      // reuses dead mnb
    float* pm             = wsf + 2097152;
    unsigned short* pmT   = (unsigned short*)(wsf + 3145728);
    float* kvbuf          = wsf + 3670016;
    float* qg             = wsf + 6291456;
    unsigned short* qTu   = (unsigned short*)(wsf + 10485760);
    // region B [12.58M,16.78M): gxbuf; then projT
    float* gxbuf          = wsf + 12582912;                       // [4][256][4096] fp32
    unsigned short* projT = (unsigned short*)(wsf + 12582912);    // [4][4096][256] bf16
    // region C [16.78M,18.78M): xT, then gxT (same slot, disjoint lifetimes)
    unsigned short* xT    = (unsigned short*)(wsf + 16777216);    // [4][4096][256] bf16
    unsigned short* gxT   = (unsigned short*)(wsf + 16777216);
    // region D: small scratch + weights
    float* part   = wsf + 18874368;
    float* stats0 = part + 512;
    float* stats1 = stats0 + 8;
    float* stats2 = stats1 + 8;
    unsigned short* wbf   = (unsigned short*)(wsf + 18875392);    // 720896 bf16
    unsigned short* wbf_qkv  = wbf;
    unsigned short* wbf_pm   = wbf + 196608;
    unsigned short* wbf_kv   = wbf + 458752;
    unsigned short* wbf_q    = wbf + 589824;
    unsigned short* wbf_proj = wbf + 655360;
    float* gobuf = out;   // d_out doubles as go scratch (dead before proj gemm writes)

    // 1. weights -> bf16
    cast_weights<<<704, 256, 0, stream>>>(qkv_w, pm_red_w, kv_w, q_w, proj_w, wbf);
    // 2. stats of x
    gn_partial<<<BATCH * 64, 256, 0, stream>>>(x, nullptr, 1048576, 64, part);
    gn_finalize<<<1, 64, 0, stream>>>(part, 64, 1.f / 1048576.f, EPS_GN, stats0, BATCH);
    // 3. xT = bf16(GN(x)) p-major
    tnc<<<dim3(64, 4, BATCH), 256, 0, stream>>>(x, nullptr, stats0, norm_w, norm_b, xT, 4096);
    // 4. qkv GEMM (MFMA)
    gemm_bf16<<<dim3(32, 12, BATCH), 256, 0, stream>>>(xT, wbf_qkv, qkv_b, qkvbuf, 256, 4096, 768);
    // 5. local windowed attention
    local_attn<<<2048, 64, 0, stream>>>(qkvbuf, gxbuf);
    // 6. stats of x+gx
    gn_partial<<<BATCH * 64, 256, 0, stream>>>(x, gxbuf, 1048576, 64, part);
    gn_finalize<<<1, 64, 0, stream>>>(part, 64, 1.f / 1048576.f, EPS_GN, stats1, BATCH);
    // 7. gxT = bf16(GN(x+gx)) p-major
    tnc<<<dim3(64, 4, BATCH), 256, 0, stream>>>(x, gxbuf, stats1, grid_norm_w, grid_norm_b, gxT, 4096);
    // 8. patch-merge LN -> mn bf16
    patch_merge_ln2<<<4096, 256, 0, stream>>>(gxT, pm_ln_w, pm_ln_b, mnb);
    // 9. patch-merge reduction GEMM (MFMA)
    gemm_bf16<<<dim3(8, 4, BATCH), 256, 0, stream>>>(mnb, wbf_pm, nullptr, pm, 1024, 1024, 256);
    // 10. stats of pm
    gn_partial<<<BATCH * 16, 256, 0, stream>>>(pm, nullptr, 262144, 16, part);
    gn_finalize<<<1, 64, 0, stream>>>(part, 16, 1.f / 262144.f, EPS_GN, stats2, BATCH);
    // 11. pmT = bf16(GN(pm)) p-major
    tnc<<<dim3(16, 4, BATCH), 256, 0, stream>>>(pm, nullptr, stats2, ds_norm_w, ds_norm_b, pmT, 1024);
    // 12. kv GEMM (MFMA)
    gemm_bf16<<<dim3(8, 8, BATCH), 256, 0, stream>>>(pmT, wbf_kv, kv_b, kvbuf, 256, 1024, 512);
    // 13. kT / vT bf16 layouts (into dead mnb region)
    transpose_cast<<<dim3(16, 8, BATCH), 256, 0, stream>>>(kvbuf, kTu, 512, 0, 1024, 1.0f);
    cast_v_bf16<<<1024, 256, 0, stream>>>(kvbuf, vTu);
    // 14. q GEMM (MFMA)
    gemm_bf16<<<dim3(32, 4, BATCH), 256, 0, stream>>>(gxT, wbf_q, q_b, qg, 256, 4096, 256);
    // 15. qT bf16 layout (scale folded)
    transpose_cast<<<dim3(64, 8, BATCH), 256, 0, stream>>>(qg, qTu, 256, 0, 4096, SCALE);
    // 16. global attention (MFMA) -> gobuf (= d_out scratch, p-major)
    global_attn_mfma<<<2048, 256, 0, stream>>>(qTu, kTu, vTu, gobuf);
    // 17. projT = bf16(gxT + go)
    proj_prep<<<4096, 256, 0, stream>>>(gxT, gobuf, projT);
    // 18. proj GEMM (MFMA) -> out
    gemm_bf16<<<dim3(32, 4, BATCH), 256, 0, stream>>>(projT, wbf_proj, proj_b, out, 256, 4096, 256);
}

// Round 5
// 294.676 us; speedup vs baseline: 3.9581x; 1.1220x over previous
//
#include <hip/hip_runtime.h>
#include <hip/hip_bf16.h>

// Problem constants
#define BATCH 4
#define CDIM 256
#define HWSZ 4096          // 64*64
#define P2 1024            // 32*32 pooled pixels per batch
#define SCALE 0.17677669529663687f
#define EPS_GN 1e-6f
#define EPS_LN 1e-5f
#define MFIX 8.0f          // fixed softmax shift (scores are O(1); exp(s-8) can't overflow)

typedef short v8s __attribute__((ext_vector_type(8)));
typedef float v4f __attribute__((ext_vector_type(4)));

__device__ __forceinline__ unsigned short f2bf(float f) {
    __hip_bfloat16 h = __float2bfloat16(f);
    return *reinterpret_cast<unsigned short*>(&h);
}
__device__ __forceinline__ float bf2f(unsigned short u) {
    return __uint_as_float(((unsigned int)u) << 16);
}
__device__ __forceinline__ unsigned int pack2(float lo, float hi) {
    return (unsigned int)f2bf(lo) | ((unsigned int)f2bf(hi) << 16);
}
__device__ __forceinline__ v8s pack8(float4 a, float4 b) {
    union { unsigned int u[4]; v8s v; } r;
    r.u[0] = pack2(a.x, a.y); r.u[1] = pack2(a.z, a.w);
    r.u[2] = pack2(b.x, b.y); r.u[3] = pack2(b.z, b.w);
    return r.v;
}
__device__ __forceinline__ void async16(void* lds, const void* g) {
    __builtin_amdgcn_global_load_lds(
        (const __attribute__((address_space(1))) unsigned int*)g,
        (__attribute__((address_space(3))) unsigned int*)lds, 16, 0, 0);
}

// ---------------- GroupNorm stats (two-stage, deterministic) ----------------
__global__ void gn_partial(const float* __restrict__ a, const float* __restrict__ a2,
                           int per_batch, int nblk, float* __restrict__ part)
{
    int bb  = blockIdx.x / nblk;
    int blk = blockIdx.x % nblk;
    const float* pa  = a  + (size_t)bb * per_batch;
    const float* pa2 = a2 ? a2 + (size_t)bb * per_batch : nullptr;
    int tid = threadIdx.x;
    float s = 0.f, s2 = 0.f;
    for (int i = blk * 256 + tid; i < per_batch; i += nblk * 256) {
        float v = pa[i];
        if (pa2) v += pa2[i];
        s += v; s2 += v * v;
    }
    __shared__ float ls[256], ls2[256];
    ls[tid] = s; ls2[tid] = s2; __syncthreads();
    for (int off = 128; off > 0; off >>= 1) {
        if (tid < off) { ls[tid] += ls[tid + off]; ls2[tid] += ls2[tid + off]; }
        __syncthreads();
    }
    if (tid == 0) {
        part[blockIdx.x * 2]     = ls[0];
        part[blockIdx.x * 2 + 1] = ls2[0];
    }
}

__global__ void gn_finalize(const float* __restrict__ part, int nblk, float inv_n,
                            float eps, float* __restrict__ stats, int nb)
{
    int b = threadIdx.x;
    if (b < nb) {
        float s = 0.f, s2 = 0.f;
        for (int i = 0; i < nblk; i++) {
            s  += part[(b * nblk + i) * 2];
            s2 += part[(b * nblk + i) * 2 + 1];
        }
        float m = s * inv_n;
        float v = s2 * inv_n - m * m;
        stats[b * 2]     = m;
        stats[b * 2 + 1] = rsqrtf(v + eps);
    }
}

// ---------------- weight cast fp32 -> bf16 (all 5 weight matrices) ----------------
__global__ void cast_weights(const float* __restrict__ w0, const float* __restrict__ w1,
                             const float* __restrict__ w2, const float* __restrict__ w3,
                             const float* __restrict__ w4, unsigned short* __restrict__ dst)
{
    int i = blockIdx.x * 256 + threadIdx.x;
    int idx = i * 4;
    const float* src; int off;
    if      (idx < 196608) { src = w0; off = 0; }
    else if (idx < 458752) { src = w1; off = 196608; }
    else if (idx < 589824) { src = w2; off = 458752; }
    else if (idx < 655360) { src = w3; off = 589824; }
    else                   { src = w4; off = 655360; }
    float4 v = *(const float4*)(src + idx - off);
    *(uint2*)(dst + idx) = make_uint2(pack2(v.x, v.y), pack2(v.z, v.w));
}

// ---------------- transpose + (optional add) + (optional norm) + cast ----------------
__global__ __launch_bounds__(256) void tnc(
    const float* __restrict__ A, const float* __restrict__ A2,
    const float* __restrict__ stats, const float* __restrict__ nw,
    const float* __restrict__ nb, unsigned short* __restrict__ dst, int P)
{
    int b = blockIdx.z, c0 = blockIdx.y * 64, p0 = blockIdx.x * 64;
    __shared__ float ld[64][65];
    int t = threadIdx.x;
    {
        int ch = t >> 2, pq = (t & 3) * 16;
        size_t base = ((size_t)b * 256 + c0 + ch) * P + p0 + pq;
        float4 f0 = *(const float4*)(A + base);
        float4 f1 = *(const float4*)(A + base + 4);
        float4 f2 = *(const float4*)(A + base + 8);
        float4 f3 = *(const float4*)(A + base + 12);
        if (A2) {
            float4 g0 = *(const float4*)(A2 + base);
            float4 g1 = *(const float4*)(A2 + base + 4);
            float4 g2 = *(const float4*)(A2 + base + 8);
            float4 g3 = *(const float4*)(A2 + base + 12);
            f0.x += g0.x; f0.y += g0.y; f0.z += g0.z; f0.w += g0.w;
            f1.x += g1.x; f1.y += g1.y; f1.z += g1.z; f1.w += g1.w;
            f2.x += g2.x; f2.y += g2.y; f2.z += g2.z; f2.w += g2.w;
            f3.x += g3.x; f3.y += g3.y; f3.z += g3.z; f3.w += g3.w;
        }
        float sw = 1.f, sb = 0.f;
        if (stats) {
            float mean = stats[b * 2], r = stats[b * 2 + 1];
            float wv = nw[c0 + ch];
            sw = r * wv; sb = nb[c0 + ch] - mean * r * wv;
        }
        ld[ch][pq + 0]  = f0.x * sw + sb; ld[ch][pq + 1]  = f0.y * sw + sb;
        ld[ch][pq + 2]  = f0.z * sw + sb; ld[ch][pq + 3]  = f0.w * sw + sb;
        ld[ch][pq + 4]  = f1.x * sw + sb; ld[ch][pq + 5]  = f1.y * sw + sb;
        ld[ch][pq + 6]  = f1.z * sw + sb; ld[ch][pq + 7]  = f1.w * sw + sb;
        ld[ch][pq + 8]  = f2.x * sw + sb; ld[ch][pq + 9]  = f2.y * sw + sb;
        ld[ch][pq + 10] = f2.z * sw + sb; ld[ch][pq + 11] = f2.w * sw + sb;
        ld[ch][pq + 12] = f3.x * sw + sb; ld[ch][pq + 13] = f3.y * sw + sb;
        ld[ch][pq + 14] = f3.z * sw + sb; ld[ch][pq + 15] = f3.w * sw + sb;
    }
    __syncthreads();
    {
        int p = t >> 2, cb = (t & 3) * 16;
        unsigned int u[8];
        #pragma unroll
        for (int j = 0; j < 8; j++)
            u[j] = pack2(ld[cb + 2 * j][p], ld[cb + 2 * j + 1][p]);
        unsigned short* dp = dst + ((size_t)b * P + p0 + p) * 256 + c0 + cb;
        *(uint4*)(dp)     = make_uint4(u[0], u[1], u[2], u[3]);
        *(uint4*)(dp + 8) = make_uint4(u[4], u[5], u[6], u[7]);
    }
}

// ---------------- MFMA GEMM: OUT[b][m][p] = sum_k actT[b][p][k]*W[m][k] + bias ----------
// QKV=false: OUT fp32 [B][OC][P].
// QKV=true : channels <512 (Q,K) -> qkp bf16 [B][4096][512] p-major;
//            channels >=512 (V)  -> vf32 fp32 [B][256][4096] c-major.
template<bool QKV>
__global__ __launch_bounds__(256) void gemm_bf16(
    const unsigned short* __restrict__ actT,
    const unsigned short* __restrict__ Wb,
    const float* __restrict__ bias,
    float* __restrict__ out,
    unsigned short* __restrict__ qkp,
    float* __restrict__ vf32,
    int K, int P, int OC)
{
    int b  = blockIdx.z;
    int p0 = blockIdx.x * 128;
    int m0 = blockIdx.y * 64;
    int tid = threadIdx.x;
    int w = tid >> 6, lane = tid & 63;
    int lm = lane & 15, lg = lane >> 4;
    int wm = w >> 1, wp = w & 1;
    int l8 = lane >> 3, cc = lane & 7;

    __shared__ __align__(16) unsigned short Wt[64 * 64];
    __shared__ __align__(16) unsigned short At[128 * 64];

    const unsigned short* actB = actT + (size_t)b * P * K;

    v4f acc[2][4];
    #pragma unroll
    for (int i = 0; i < 2; i++)
        #pragma unroll
        for (int j = 0; j < 4; j++) acc[i][j] = (v4f){0.f, 0.f, 0.f, 0.f};

    for (int ks = 0; ks < K; ks += 64) {
        #pragma unroll
        for (int i = 0; i < 2; i++) {
            int ml = w * 16 + i * 8 + l8;
            int g = cc ^ (ml & 7);
            async16(&Wt[(w * 16 + i * 8) * 64], Wb + (size_t)(m0 + ml) * K + ks + g * 8);
        }
        #pragma unroll
        for (int i = 0; i < 4; i++) {
            int pl = w * 32 + i * 8 + l8;
            int g = cc ^ (pl & 7);
            async16(&At[(w * 32 + i * 8) * 64], actB + (size_t)(p0 + pl) * K + ks + g * 8);
        }
        __syncthreads();
        #pragma unroll
        for (int kk = 0; kk < 2; kk++) {
            v8s af[2], bfv[4];
            #pragma unroll
            for (int mt = 0; mt < 2; mt++) {
                int m = wm * 32 + mt * 16 + lm;
                int ch = (kk * 4 + lg) ^ (m & 7);
                af[mt] = *(const v8s*)&Wt[m * 64 + ch * 8];
            }
            #pragma unroll
            for (int pt = 0; pt < 4; pt++) {
                int p = wp * 64 + pt * 16 + lm;
                int ch = (kk * 4 + lg) ^ (p & 7);
                bfv[pt] = *(const v8s*)&At[p * 64 + ch * 8];
            }
            #pragma unroll
            for (int mt = 0; mt < 2; mt++)
                #pragma unroll
                for (int pt = 0; pt < 4; pt++)
                    acc[mt][pt] = __builtin_amdgcn_mfma_f32_16x16x32_bf16(
                        af[mt], bfv[pt], acc[mt][pt], 0, 0, 0);
        }
        __syncthreads();
    }

    if constexpr (QKV) {
        if (m0 < 512) {
            // Q,K -> p-major bf16 [b][p][512]
            #pragma unroll
            for (int mt = 0; mt < 2; mt++) {
                int mch = m0 + wm * 32 + mt * 16 + lg * 4;
                float4 bs = *(const float4*)(bias + mch);
                #pragma unroll
                for (int pt = 0; pt < 4; pt++) {
                    int p = p0 + wp * 64 + pt * 16 + lm;
                    unsigned int u0 = pack2(acc[mt][pt][0] + bs.x, acc[mt][pt][1] + bs.y);
                    unsigned int u1 = pack2(acc[mt][pt][2] + bs.z, acc[mt][pt][3] + bs.w);
                    *(uint2*)(qkp + ((size_t)(b * 4096 + p) * 512 + mch)) = make_uint2(u0, u1);
                }
            }
        } else {
            // V -> c-major fp32 [b][256][4096]
            #pragma unroll
            for (int mt = 0; mt < 2; mt++) {
                #pragma unroll
                for (int r = 0; r < 4; r++) {
                    int m = m0 + wm * 32 + mt * 16 + lg * 4 + r;
                    float bsv = bias[m];
                    float* orow = vf32 + ((size_t)b * 256 + (m - 512)) * 4096 + p0 + wp * 64;
                    #pragma unroll
                    for (int pt = 0; pt < 4; pt++)
                        orow[pt * 16 + lm] = acc[mt][pt][r] + bsv;
                }
            }
        }
    } else {
        #pragma unroll
        for (int mt = 0; mt < 2; mt++) {
            #pragma unroll
            for (int r = 0; r < 4; r++) {
                int m = m0 + wm * 32 + mt * 16 + lg * 4 + r;
                float bs = bias ? bias[m] : 0.f;
                float* orow = out + (size_t)b * OC * P + (size_t)m * P + p0 + wp * 64;
                #pragma unroll
                for (int pt = 0; pt < 4; pt++)
                    orow[pt * 16 + lm] = acc[mt][pt][r] + bs;
            }
        }
    }
}

// ---------------- local windowed attention, bf16 MFMA, fixed-max ----------------
// qkp: [B][4096][512] bf16 (Q ch 0-255, K ch 256-511); vf32: [B][256][4096] fp32.
// gx:  [B][256][4096] fp32 c-major.  One window per block; wave w = q-tile w.
__global__ __launch_bounds__(256) void local_attn_mfma(
    const unsigned short* __restrict__ qkp,
    const float* __restrict__ vf32,
    float* __restrict__ gx)
{
    int win = blockIdx.x;                  // b*512 + h*64 + gy*8 + gxc
    int gxc = win & 7, gy = (win >> 3) & 7, h = (win >> 6) & 7, b = win >> 9;
    int w = threadIdx.x >> 6, lane = threadIdx.x & 63;
    int m = lane & 15, g = lane >> 4;

    __shared__ __align__(16) unsigned char plds[4][2048];
    unsigned char* pl = plds[w];

    int rowbase = (gy * 8) * 64 + gxc * 8;   // pixel of window token 0
    const unsigned short* qkb = qkp + (size_t)b * 4096 * 512;
    const float* vbase = vf32 + (size_t)b * 256 * 4096;

    // Q-frag (B-op): query token w*16+m
    int tq = w * 16 + m;
    int pq = rowbase + (tq >> 3) * 64 + (tq & 7);
    v8s qf = *(const v8s*)(qkb + (size_t)pq * 512 + h * 32 + g * 8);

    // K-frags (A-op): key tokens kt*16+m
    v8s ka[4];
    #pragma unroll
    for (int kt = 0; kt < 4; kt++) {
        int tk = kt * 16 + m;
        int pk = rowbase + (tk >> 3) * 64 + (tk & 7);
        ka[kt] = *(const v8s*)(qkb + (size_t)pk * 512 + 256 + h * 32 + g * 8);
    }
    // V-frags (B-op of PV): keys c*32+g*8..+7 (one pixel row), d = dt*16+m
    v8s vb[2][2];
    #pragma unroll
    for (int c = 0; c < 2; c++)
        #pragma unroll
        for (int dt = 0; dt < 2; dt++) {
            int tv = c * 32 + g * 8;               // (tv&7)==0 -> full 8-pixel run
            int pv = rowbase + (tv >> 3) * 64;
            const float* vp = vbase + (size_t)(h * 32 + dt * 16 + m) * 4096 + pv;
            vb[c][dt] = pack8(*(const float4*)vp, *(const float4*)(vp + 4));
        }

    const v4f zf = {0.f, 0.f, 0.f, 0.f};
    v4f s[4];
    #pragma unroll
    for (int kt = 0; kt < 4; kt++)
        s[kt] = __builtin_amdgcn_mfma_f32_16x16x32_bf16(ka[kt], qf, zf, 0, 0, 0);

    // fixed-max softmax numerators; pack P^T to per-wave LDS
    float lsum = 0.f;
    #pragma unroll
    for (int kt = 0; kt < 4; kt++) {
        float p0 = __expf(fmaf(s[kt][0], SCALE, -MFIX));
        float p1 = __expf(fmaf(s[kt][1], SCALE, -MFIX));
        float p2 = __expf(fmaf(s[kt][2], SCALE, -MFIX));
        float p3 = __expf(fmaf(s[kt][3], SCALE, -MFIX));
        lsum += (p0 + p1) + (p2 + p3);
        int slot = kt * 2 + (g >> 1);
        unsigned char* bp = pl + m * 128 + ((slot ^ (m & 7)) << 4) + (g & 1) * 8;
        *(uint2*)bp = make_uint2(pack2(p0, p1), pack2(p2, p3));
    }
    lsum += __shfl_xor(lsum, 16);
    lsum += __shfl_xor(lsum, 32);
    float inv = 1.f / lsum;

    v4f o0 = zf, o1 = zf;
    #pragma unroll
    for (int c = 0; c < 2; c++) {
        v8s pa = *(const v8s*)(pl + m * 128 + (((c * 4 + g) ^ (m & 7)) << 4));
        o0 = __builtin_amdgcn_mfma_f32_16x16x32_bf16(pa, vb[c][0], o0, 0, 0, 0);
        o1 = __builtin_amdgcn_mfma_f32_16x16x32_bf16(pa, vb[c][1], o1, 0, 0, 0);
    }
    float invq[4];
    #pragma unroll
    for (int r = 0; r < 4; r++) invq[r] = __shfl(inv, g * 4 + r);

    int t0 = w * 16 + g * 4;                     // 4 consecutive tokens, same pixel row
    int px0 = rowbase + (t0 >> 3) * 64 + (t0 & 7);
    float* op0 = gx + ((size_t)b * 256 + h * 32 + m) * 4096 + px0;
    *(float4*)op0 = make_float4(o0[0] * invq[0], o0[1] * invq[1], o0[2] * invq[2], o0[3] * invq[3]);
    float* op1 = gx + ((size_t)b * 256 + h * 32 + 16 + m) * 4096 + px0;
    *(float4*)op1 = make_float4(o1[0] * invq[0], o1[1] * invq[1], o1[2] * invq[2], o1[3] * invq[3]);
}

// ---------------- patch-merge layernorm (reads coalesced gxT, writes bf16 mn) ----------
__global__ __launch_bounds__(256) void patch_merge_ln2(
    const unsigned short* __restrict__ gxT,
    const float* __restrict__ lnw, const float* __restrict__ lnb,
    unsigned short* __restrict__ mn)
{
    int pix = blockIdx.x;
    int b = pix >> 10, op = pix & 1023;
    int oh = op >> 5, ow = op & 31;
    int t = threadIdx.x;
    const unsigned short* base = gxT + (size_t)b * 4096 * 256;
    float v[4];
    #pragma unroll
    for (int i = 0; i < 4; i++) {
        int h = 2 * oh + (i & 1);
        int w = 2 * ow + (i >> 1);
        v[i] = bf2f(base[(size_t)(h * 64 + w) * 256 + t]);
    }
    float s  = v[0] + v[1] + v[2] + v[3];
    float s2 = v[0]*v[0] + v[1]*v[1] + v[2]*v[2] + v[3]*v[3];
    __shared__ float ls[256], ls2[256];
    ls[t] = s; ls2[t] = s2; __syncthreads();
    for (int off = 128; off > 0; off >>= 1) {
        if (t < off) { ls[t] += ls[t + off]; ls2[t] += ls2[t + off]; }
        __syncthreads();
    }
    float mu  = ls[0] * (1.f / 1024.f);
    float var = ls2[0] * (1.f / 1024.f) - mu * mu;
    float r = rsqrtf(var + EPS_LN);
    unsigned short* orow = mn + (size_t)pix * 1024;
    #pragma unroll
    for (int i = 0; i < 4; i++) {
        int j = i * 256 + t;
        orow[j] = f2bf((v[i] - mu) * r * lnw[j] + lnb[j]);
    }
}

// ---------------- transpose + cast: fp32 [B,Csrc,P] (32-ch slab per head) -> bf16 [B*8, P, 32]
__global__ __launch_bounds__(256) void transpose_cast(
    const float* __restrict__ src, unsigned short* __restrict__ dst,
    int Csrc, int coff, int P, float scale)
{
    int b = blockIdx.z, h = blockIdx.y, p0 = blockIdx.x * 64;
    __shared__ float ld[32][65];
    int t = threadIdx.x;
    {
        int d = t >> 3, pb = (t & 7) * 8;
        const float* s = src + ((size_t)b * Csrc + coff + h * 32 + d) * P + p0 + pb;
        float4 v0 = *(const float4*)s;
        float4 v1 = *(const float4*)(s + 4);
        ld[d][pb + 0] = v0.x; ld[d][pb + 1] = v0.y; ld[d][pb + 2] = v0.z; ld[d][pb + 3] = v0.w;
        ld[d][pb + 4] = v1.x; ld[d][pb + 5] = v1.y; ld[d][pb + 6] = v1.z; ld[d][pb + 7] = v1.w;
    }
    __syncthreads();
    {
        int q = t >> 2, slot = t & 3;
        unsigned int u[4];
        #pragma unroll
        for (int wds = 0; wds < 4; wds++)
            u[wds] = pack2(ld[slot * 8 + wds * 2][q] * scale,
                           ld[slot * 8 + wds * 2 + 1][q] * scale);
        unsigned short* dp = dst + ((size_t)(b * 8 + h) * P + p0 + q) * 32 + slot * 8;
        *(uint4*)dp = make_uint4(u[0], u[1], u[2], u[3]);
    }
}

// ---------------- elementwise cast: V half of kv fp32 [B,512,1024] -> bf16 [B*8,32,1024]
__global__ __launch_bounds__(256) void cast_v_bf16(
    const float* __restrict__ kv, unsigned short* __restrict__ vT)
{
    int i = blockIdx.x * 256 + threadIdx.x;
    int b = i >> 16, r4 = i & 65535;
    const float4 v = *(const float4*)(kv + (size_t)b * 524288 + 262144 + (size_t)r4 * 4);
    *(uint2*)(vT + (size_t)b * 262144 + (size_t)r4 * 4) =
        make_uint2(pack2(v.x, v.y), pack2(v.z, v.w));
}

// ---------------- global attention, bf16 MFMA flash, fixed-max, barrier-free ----------------
__global__ __launch_bounds__(256) void global_attn_mfma(
    const unsigned short* __restrict__ qT,
    const unsigned short* __restrict__ kT,
    const unsigned short* __restrict__ vT,
    float* __restrict__ go)
{
    int blk = blockIdx.x;
    int qt = blk & 63, h = (blk >> 6) & 7, b = blk >> 9;
    int bh = b * 8 + h;
    int w = threadIdx.x >> 6, lane = threadIdx.x & 63;
    int m = lane & 15, g = lane >> 4;
    int qbase = qt * 64 + w * 16;

    __shared__ __align__(16) unsigned char plds[4][2][2048];  // per-wave, double-buffered

    v8s qf = *(const v8s*)(qT + ((size_t)bh * 4096 + qbase + m) * 32 + g * 8);

    v4f o0 = {0.f, 0.f, 0.f, 0.f}, o1 = {0.f, 0.f, 0.f, 0.f};
    float l_run = 0.f;
    const v4f zf = {0.f, 0.f, 0.f, 0.f};

    #pragma unroll 1
    for (int t = 0; t < 16; t++) {
        unsigned char* pl = plds[w][t & 1];
        int k0 = t * 64;
        const unsigned short* kp = kT + ((size_t)bh * 1024 + k0 + m) * 32 + g * 8;
        v8s ka0 = *(const v8s*)(kp);
        v8s ka1 = *(const v8s*)(kp + 16 * 32);
        v8s ka2 = *(const v8s*)(kp + 32 * 32);
        v8s ka3 = *(const v8s*)(kp + 48 * 32);
        v4f s[4];
        s[0] = __builtin_amdgcn_mfma_f32_16x16x32_bf16(ka0, qf, zf, 0, 0, 0);
        s[1] = __builtin_amdgcn_mfma_f32_16x16x32_bf16(ka1, qf, zf, 0, 0, 0);
        s[2] = __builtin_amdgcn_mfma_f32_16x16x32_bf16(ka2, qf, zf, 0, 0, 0);
        s[3] = __builtin_amdgcn_mfma_f32_16x16x32_bf16(ka3, qf, zf, 0, 0, 0);

        float lsum = 0.f;
        #pragma unroll
        for (int kt = 0; kt < 4; kt++) {
            float p0 = __expf(s[kt][0] - MFIX);
            float p1 = __expf(s[kt][1] - MFIX);
            float p2 = __expf(s[kt][2] - MFIX);
            float p3 = __expf(s[kt][3] - MFIX);
            lsum += (p0 + p1) + (p2 + p3);
            int slot = kt * 2 + (g >> 1);
            unsigned char* bp = pl + m * 128 + ((slot ^ (m & 7)) << 4) + (g & 1) * 8;
            *(uint2*)bp = make_uint2(pack2(p0, p1), pack2(p2, p3));
        }
        l_run += lsum;

        #pragma unroll
        for (int c = 0; c < 2; c++) {
            v8s pa = *(const v8s*)(pl + m * 128 + (((c * 4 + g) ^ (m & 7)) << 4));
            const unsigned short* vp = vT + ((size_t)bh * 32 + m) * 1024 + k0 + c * 32 + g * 8;
            v8s vb0 = *(const v8s*)(vp);
            v8s vb1 = *(const v8s*)(vp + 16 * 1024);
            o0 = __builtin_amdgcn_mfma_f32_16x16x32_bf16(pa, vb0, o0, 0, 0, 0);
            o1 = __builtin_amdgcn_mfma_f32_16x16x32_bf16(pa, vb1, o1, 0, 0, 0);
        }
    }

    float lf = l_run;
    lf += __shfl_xor(lf, 16);
    lf += __shfl_xor(lf, 32);
    float inv = 1.f / lf;
    float invq[4];
    #pragma unroll
    for (int r = 0; r < 4; r++) invq[r] = __shfl(inv, g * 4 + r);

    #pragma unroll
    for (int r = 0; r < 4; r++) {
        size_t row = ((size_t)b * 4096 + qbase + g * 4 + r) * 256 + h * 32;
        go[row + m]      = o0[r] * invq[r];
        go[row + 16 + m] = o1[r] * invq[r];
    }
}

// ---------------- proj input: projT[p][c] = bf16(gxT + go) ----------------
__global__ void proj_prep(const unsigned short* __restrict__ gxT,
                          const float* __restrict__ go,
                          unsigned short* __restrict__ projT)
{
    size_t i = ((size_t)blockIdx.x * 256 + threadIdx.x) * 4;
    uint2 gv = *(const uint2*)(gxT + i);
    float4 gof = *(const float4*)(go + i);
    float a0 = __uint_as_float(gv.x << 16) + gof.x;
    float a1 = __uint_as_float(gv.x & 0xffff0000u) + gof.y;
    float a2 = __uint_as_float(gv.y << 16) + gof.z;
    float a3 = __uint_as_float(gv.y & 0xffff0000u) + gof.w;
    *(uint2*)(projT + i) = make_uint2(pack2(a0, a1), pack2(a2, a3));
}

// ---------------- launcher ----------------
extern "C" void kernel_launch(void* const* d_in, const int* in_sizes, int n_in,
                              void* d_out, int out_size, void* d_ws, size_t ws_size,
                              hipStream_t stream)
{
    const float* x           = (const float*)d_in[0];
    const float* norm_w      = (const float*)d_in[1];
    const float* norm_b      = (const float*)d_in[2];
    const float* qkv_w       = (const float*)d_in[3];
    const float* qkv_b       = (const float*)d_in[4];
    const float* proj_w      = (const float*)d_in[5];
    const float* proj_b      = (const float*)d_in[6];
    const float* grid_norm_w = (const float*)d_in[7];
    const float* grid_norm_b = (const float*)d_in[8];
    const float* pm_ln_w     = (const float*)d_in[9];
    const float* pm_ln_b     = (const float*)d_in[10];
    const float* pm_red_w    = (const float*)d_in[11];
    const float* ds_norm_w   = (const float*)d_in[12];
    const float* ds_norm_b   = (const float*)d_in[13];
    const float* q_w         = (const float*)d_in[14];
    const float* q_b         = (const float*)d_in[15];
    const float* kv_w        = (const float*)d_in[16];
    const float* kv_b        = (const float*)d_in[17];
    float* out = (float*)d_out;

    float* wsf = (float*)d_ws;
    // region A [0, 12.58M floats) — float-slot accounting, disjoint lifetimes:
    //   qkp    [0, 4,194,304)            bf16 [4][4096][512]  (steps 4-5)
    //   vf32   [4,194,304, 8,388,608)    fp32 [4][256][4096]  (steps 4-5)
    //   mnb    [0, 2,097,152)            bf16 [4096][1024]    (steps 8-9)
    //   kTu    [0, 524,288)              bf16 [32][1024][32]  (steps 13-16)
    //   vTu    [524,288, 1,048,576)      bf16 [32][32][1024]  (steps 13-16)
    //   pm     [2,097,152, 3,145,728)    fp32 [4][256][1024]  (steps 9-11)
    //   pmT    [3,145,728, 3,670,016)    bf16 [4][1024][256]  (steps 11-12)
    //   kvbuf  [3,670,016, 5,767,168)    fp32 [4][512][1024]  (steps 12-13)
    //   qg     [6,291,456, 10,485,760)   fp32 [4][256][4096]  (steps 14-15)
    //   qTu    [10,485,760, 12,582,912)  bf16 [32][4096][32]  (steps 15-16)
    unsigned short* qkp   = (unsigned short*)(wsf);
    float* vf32           = wsf + 4194304;
    unsigned short* mnb   = (unsigned short*)(wsf);
    unsigned short* kTu   = (unsigned short*)(wsf);
    unsigned short* vTu   = (unsigned short*)(wsf + 524288);
    float* pm             = wsf + 2097152;
    unsigned short* pmT   = (unsigned short*)(wsf + 3145728);
    float* kvbuf          = wsf + 3670016;
    float* qg             = wsf + 6291456;
    unsigned short* qTu   = (unsigned short*)(wsf + 10485760);
    // region B [12.58M,16.78M): gxbuf; then projT
    float* gxbuf          = wsf + 12582912;
    unsigned short* projT = (unsigned short*)(wsf + 12582912);
    // region C [16.78M,18.78M): xT, then gxT
    unsigned short* xT    = (unsigned short*)(wsf + 16777216);
    unsigned short* gxT   = (unsigned short*)(wsf + 16777216);
    // region D: small scratch + weights
    float* part   = wsf + 18874368;
    float* stats0 = part + 512;
    float* stats1 = stats0 + 8;
    float* stats2 = stats1 + 8;
    unsigned short* wbf   = (unsigned short*)(wsf + 18875392);
    unsigned short* wbf_qkv  = wbf;
    unsigned short* wbf_pm   = wbf + 196608;
    unsigned short* wbf_kv   = wbf + 458752;
    unsigned short* wbf_q    = wbf + 589824;
    unsigned short* wbf_proj = wbf + 655360;
    float* gobuf = out;   // d_out doubles as go scratch

    // 1. weights -> bf16
    cast_weights<<<704, 256, 0, stream>>>(qkv_w, pm_red_w, kv_w, q_w, proj_w, wbf);
    // 2. stats of x
    gn_partial<<<BATCH * 64, 256, 0, stream>>>(x, nullptr, 1048576, 64, part);
    gn_finalize<<<1, 64, 0, stream>>>(part, 64, 1.f / 1048576.f, EPS_GN, stats0, BATCH);
    // 3. xT = bf16(GN(x)) p-major
    tnc<<<dim3(64, 4, BATCH), 256, 0, stream>>>(x, nullptr, stats0, norm_w, norm_b, xT, 4096);
    // 4. qkv GEMM (MFMA) -> qkp (Q,K p-major bf16) + vf32 (V c-major fp32)
    gemm_bf16<true><<<dim3(32, 12, BATCH), 256, 0, stream>>>(
        xT, wbf_qkv, qkv_b, nullptr, qkp, vf32, 256, 4096, 768);
    // 5. local windowed attention (MFMA) -> gxbuf fp32 c-major
    local_attn_mfma<<<2048, 256, 0, stream>>>(qkp, vf32, gxbuf);
    // 6. stats of x+gx
    gn_partial<<<BATCH * 64, 256, 0, stream>>>(x, gxbuf, 1048576, 64, part);
    gn_finalize<<<1, 64, 0, stream>>>(part, 64, 1.f / 1048576.f, EPS_GN, stats1, BATCH);
    // 7. gxT = bf16(GN(x+gx)) p-major
    tnc<<<dim3(64, 4, BATCH), 256, 0, stream>>>(x, gxbuf, stats1, grid_norm_w, grid_norm_b, gxT, 4096);
    // 8. patch-merge LN -> mn bf16
    patch_merge_ln2<<<4096, 256, 0, stream>>>(gxT, pm_ln_w, pm_ln_b, mnb);
    // 9. patch-merge reduction GEMM (MFMA)
    gemm_bf16<false><<<dim3(8, 4, BATCH), 256, 0, stream>>>(
        mnb, wbf_pm, nullptr, pm, nullptr, nullptr, 1024, 1024, 256);
    // 10. stats of pm
    gn_partial<<<BATCH * 16, 256, 0, stream>>>(pm, nullptr, 262144, 16, part);
    gn_finalize<<<1, 64, 0, stream>>>(part, 16, 1.f / 262144.f, EPS_GN, stats2, BATCH);
    // 11. pmT = bf16(GN(pm)) p-major
    tnc<<<dim3(16, 4, BATCH), 256, 0, stream>>>(pm, nullptr, stats2, ds_norm_w, ds_norm_b, pmT, 1024);
    // 12. kv GEMM (MFMA)
    gemm_bf16<false><<<dim3(8, 8, BATCH), 256, 0, stream>>>(
        pmT, wbf_kv, kv_b, kvbuf, nullptr, nullptr, 256, 1024, 512);
    // 13. kT / vT bf16 layouts (into dead mnb region)
    transpose_cast<<<dim3(16, 8, BATCH), 256, 0, stream>>>(kvbuf, kTu, 512, 0, 1024, 1.0f);
    cast_v_bf16<<<1024, 256, 0, stream>>>(kvbuf, vTu);
    // 14. q GEMM (MFMA)
    gemm_bf16<false><<<dim3(32, 4, BATCH), 256, 0, stream>>>(
        gxT, wbf_q, q_b, qg, nullptr, nullptr, 256, 4096, 256);
    // 15. qT bf16 layout (scale folded)
    transpose_cast<<<dim3(64, 8, BATCH), 256, 0, stream>>>(qg, qTu, 256, 0, 4096, SCALE);
    // 16. global attention (MFMA) -> gobuf (= d_out scratch, p-major)
    global_attn_mfma<<<2048, 256, 0, stream>>>(qTu, kTu, vTu, gobuf);
    // 17. projT = bf16(gxT + go)
    proj_prep<<<4096, 256, 0, stream>>>(gxT, gobuf, projT);
    // 18. proj GEMM (MFMA) -> out
    gemm_bf16<false><<<dim3(32, 4, BATCH), 256, 0, stream>>>(
        projT, wbf_proj, proj_b, out, nullptr, nullptr, 256, 4096, 256);
}

// Round 6
// 269.911 us; speedup vs baseline: 4.3213x; 1.0917x over previous
//
#include <hip/hip_runtime.h>
#include <hip/hip_bf16.h>

// Problem constants
#define BATCH 4
#define CDIM 256
#define HWSZ 4096          // 64*64
#define P2 1024            // 32*32 pooled pixels per batch
#define SCALE 0.17677669529663687f
#define EPS_GN 1e-6f
#define EPS_LN 1e-5f
#define MFIX 8.0f          // fixed softmax shift (scores are O(1); exp(s-8) can't overflow)

typedef short v8s __attribute__((ext_vector_type(8)));
typedef float v4f __attribute__((ext_vector_type(4)));

__device__ __forceinline__ unsigned short f2bf(float f) {
    __hip_bfloat16 h = __float2bfloat16(f);
    return *reinterpret_cast<unsigned short*>(&h);
}
__device__ __forceinline__ float bf2f(unsigned short u) {
    return __uint_as_float(((unsigned int)u) << 16);
}
__device__ __forceinline__ unsigned int pack2(float lo, float hi) {
    return (unsigned int)f2bf(lo) | ((unsigned int)f2bf(hi) << 16);
}
__device__ __forceinline__ v8s pack8(float4 a, float4 b) {
    union { unsigned int u[4]; v8s v; } r;
    r.u[0] = pack2(a.x, a.y); r.u[1] = pack2(a.z, a.w);
    r.u[2] = pack2(b.x, b.y); r.u[3] = pack2(b.z, b.w);
    return r.v;
}
__device__ __forceinline__ v8s pack8p(const float* p) {
    union { unsigned int u[4]; v8s v; } r;
    r.u[0] = pack2(p[0], p[1]); r.u[1] = pack2(p[2], p[3]);
    r.u[2] = pack2(p[4], p[5]); r.u[3] = pack2(p[6], p[7]);
    return r.v;
}
// V key permutation within a 64-key block: S^T reg order -> PV A-frag contract order.
// j = [b5 b4 | b3 b2 | b1 b0] -> j' = [b5 | b3 b2 | b4 | b1 b0]
__device__ __forceinline__ int vperm(int j) {
    return (j & 0x23) | ((j & 0x0C) << 1) | ((j & 0x10) >> 2);
}
__device__ __forceinline__ void async16(void* lds, const void* g) {
    __builtin_amdgcn_global_load_lds(
        (const __attribute__((address_space(1))) unsigned int*)g,
        (__attribute__((address_space(3))) unsigned int*)lds, 16, 0, 0);
}

// ---------------- GroupNorm stats (two-stage, deterministic) ----------------
__global__ void gn_partial(const float* __restrict__ a, const float* __restrict__ a2,
                           int per_batch, int nblk, float* __restrict__ part)
{
    int bb  = blockIdx.x / nblk;
    int blk = blockIdx.x % nblk;
    const float* pa  = a  + (size_t)bb * per_batch;
    const float* pa2 = a2 ? a2 + (size_t)bb * per_batch : nullptr;
    int tid = threadIdx.x;
    float s = 0.f, s2 = 0.f;
    for (int i = blk * 256 + tid; i < per_batch; i += nblk * 256) {
        float v = pa[i];
        if (pa2) v += pa2[i];
        s += v; s2 += v * v;
    }
    __shared__ float ls[256], ls2[256];
    ls[tid] = s; ls2[tid] = s2; __syncthreads();
    for (int off = 128; off > 0; off >>= 1) {
        if (tid < off) { ls[tid] += ls[tid + off]; ls2[tid] += ls2[tid + off]; }
        __syncthreads();
    }
    if (tid == 0) {
        part[blockIdx.x * 2]     = ls[0];
        part[blockIdx.x * 2 + 1] = ls2[0];
    }
}

__global__ void gn_finalize(const float* __restrict__ part, int nblk, float inv_n,
                            float eps, float* __restrict__ stats, int nb)
{
    int b = threadIdx.x;
    if (b < nb) {
        float s = 0.f, s2 = 0.f;
        for (int i = 0; i < nblk; i++) {
            s  += part[(b * nblk + i) * 2];
            s2 += part[(b * nblk + i) * 2 + 1];
        }
        float m = s * inv_n;
        float v = s2 * inv_n - m * m;
        stats[b * 2]     = m;
        stats[b * 2 + 1] = rsqrtf(v + eps);
    }
}

// ---------------- weight cast fp32 -> bf16 (all 5 weight matrices) ----------------
__global__ void cast_weights(const float* __restrict__ w0, const float* __restrict__ w1,
                             const float* __restrict__ w2, const float* __restrict__ w3,
                             const float* __restrict__ w4, unsigned short* __restrict__ dst)
{
    int i = blockIdx.x * 256 + threadIdx.x;
    int idx = i * 4;
    const float* src; int off;
    if      (idx < 196608) { src = w0; off = 0; }
    else if (idx < 458752) { src = w1; off = 196608; }
    else if (idx < 589824) { src = w2; off = 458752; }
    else if (idx < 655360) { src = w3; off = 589824; }
    else                   { src = w4; off = 655360; }
    float4 v = *(const float4*)(src + idx - off);
    *(uint2*)(dst + idx) = make_uint2(pack2(v.x, v.y), pack2(v.z, v.w));
}

// ---------------- transpose + (optional add) + (optional norm) + cast ----------------
__global__ __launch_bounds__(256) void tnc(
    const float* __restrict__ A, const float* __restrict__ A2,
    const float* __restrict__ stats, const float* __restrict__ nw,
    const float* __restrict__ nb, unsigned short* __restrict__ dst, int P)
{
    int b = blockIdx.z, c0 = blockIdx.y * 64, p0 = blockIdx.x * 64;
    __shared__ float ld[64][65];
    int t = threadIdx.x;
    {
        int ch = t >> 2, pq = (t & 3) * 16;
        size_t base = ((size_t)b * 256 + c0 + ch) * P + p0 + pq;
        float4 f0 = *(const float4*)(A + base);
        float4 f1 = *(const float4*)(A + base + 4);
        float4 f2 = *(const float4*)(A + base + 8);
        float4 f3 = *(const float4*)(A + base + 12);
        if (A2) {
            float4 g0 = *(const float4*)(A2 + base);
            float4 g1 = *(const float4*)(A2 + base + 4);
            float4 g2 = *(const float4*)(A2 + base + 8);
            float4 g3 = *(const float4*)(A2 + base + 12);
            f0.x += g0.x; f0.y += g0.y; f0.z += g0.z; f0.w += g0.w;
            f1.x += g1.x; f1.y += g1.y; f1.z += g1.z; f1.w += g1.w;
            f2.x += g2.x; f2.y += g2.y; f2.z += g2.z; f2.w += g2.w;
            f3.x += g3.x; f3.y += g3.y; f3.z += g3.z; f3.w += g3.w;
        }
        float sw = 1.f, sb = 0.f;
        if (stats) {
            float mean = stats[b * 2], r = stats[b * 2 + 1];
            float wv = nw[c0 + ch];
            sw = r * wv; sb = nb[c0 + ch] - mean * r * wv;
        }
        ld[ch][pq + 0]  = f0.x * sw + sb; ld[ch][pq + 1]  = f0.y * sw + sb;
        ld[ch][pq + 2]  = f0.z * sw + sb; ld[ch][pq + 3]  = f0.w * sw + sb;
        ld[ch][pq + 4]  = f1.x * sw + sb; ld[ch][pq + 5]  = f1.y * sw + sb;
        ld[ch][pq + 6]  = f1.z * sw + sb; ld[ch][pq + 7]  = f1.w * sw + sb;
        ld[ch][pq + 8]  = f2.x * sw + sb; ld[ch][pq + 9]  = f2.y * sw + sb;
        ld[ch][pq + 10] = f2.z * sw + sb; ld[ch][pq + 11] = f2.w * sw + sb;
        ld[ch][pq + 12] = f3.x * sw + sb; ld[ch][pq + 13] = f3.y * sw + sb;
        ld[ch][pq + 14] = f3.z * sw + sb; ld[ch][pq + 15] = f3.w * sw + sb;
    }
    __syncthreads();
    {
        int p = t >> 2, cb = (t & 3) * 16;
        unsigned int u[8];
        #pragma unroll
        for (int j = 0; j < 8; j++)
            u[j] = pack2(ld[cb + 2 * j][p], ld[cb + 2 * j + 1][p]);
        unsigned short* dp = dst + ((size_t)b * P + p0 + p) * 256 + c0 + cb;
        *(uint4*)(dp)     = make_uint4(u[0], u[1], u[2], u[3]);
        *(uint4*)(dp + 8) = make_uint4(u[4], u[5], u[6], u[7]);
    }
}

// ---------------- MFMA GEMM: OUT[b][m][p] = sum_k actT[b][p][k]*W[m][k] + bias ----------
// MODE 0: OUT fp32 c-major [B][OC][P].
// MODE 1: qkv split -> aux1 = qkp bf16 [B][4096][512] p-major (ch<512), vf32 c-major (ch>=512).
// MODE 2: head-split p-major bf16 [B*8][P][32], (acc+bias)*oscale  (Q path).
// MODE 3: kv: ch<256 (K) -> aux1 [B*8][1024][32] p-major; ch>=256 (V) -> aux2 [B*8][32][1024]
//         c-major with vperm'd key positions.
template<int MODE>
__global__ __launch_bounds__(256) void gemm_bf16(
    const unsigned short* __restrict__ actT,
    const unsigned short* __restrict__ Wb,
    const float* __restrict__ bias,
    float* __restrict__ out,
    unsigned short* __restrict__ aux1,
    unsigned short* __restrict__ aux2,
    float* __restrict__ vf32,
    int K, int P, int OC, float oscale)
{
    int b  = blockIdx.z;
    int p0 = blockIdx.x * 128;
    int m0 = blockIdx.y * 64;
    int tid = threadIdx.x;
    int w = tid >> 6, lane = tid & 63;
    int lm = lane & 15, lg = lane >> 4;
    int wm = w >> 1, wp = w & 1;
    int l8 = lane >> 3, cc = lane & 7;

    __shared__ __align__(16) unsigned short Wt[64 * 64];
    __shared__ __align__(16) unsigned short At[128 * 64];

    const unsigned short* actB = actT + (size_t)b * P * K;

    v4f acc[2][4];
    #pragma unroll
    for (int i = 0; i < 2; i++)
        #pragma unroll
        for (int j = 0; j < 4; j++) acc[i][j] = (v4f){0.f, 0.f, 0.f, 0.f};

    for (int ks = 0; ks < K; ks += 64) {
        #pragma unroll
        for (int i = 0; i < 2; i++) {
            int ml = w * 16 + i * 8 + l8;
            int g = cc ^ (ml & 7);
            async16(&Wt[(w * 16 + i * 8) * 64], Wb + (size_t)(m0 + ml) * K + ks + g * 8);
        }
        #pragma unroll
        for (int i = 0; i < 4; i++) {
            int pl = w * 32 + i * 8 + l8;
            int g = cc ^ (pl & 7);
            async16(&At[(w * 32 + i * 8) * 64], actB + (size_t)(p0 + pl) * K + ks + g * 8);
        }
        __syncthreads();
        #pragma unroll
        for (int kk = 0; kk < 2; kk++) {
            v8s af[2], bfv[4];
            #pragma unroll
            for (int mt = 0; mt < 2; mt++) {
                int m = wm * 32 + mt * 16 + lm;
                int ch = (kk * 4 + lg) ^ (m & 7);
                af[mt] = *(const v8s*)&Wt[m * 64 + ch * 8];
            }
            #pragma unroll
            for (int pt = 0; pt < 4; pt++) {
                int p = wp * 64 + pt * 16 + lm;
                int ch = (kk * 4 + lg) ^ (p & 7);
                bfv[pt] = *(const v8s*)&At[p * 64 + ch * 8];
            }
            #pragma unroll
            for (int mt = 0; mt < 2; mt++)
                #pragma unroll
                for (int pt = 0; pt < 4; pt++)
                    acc[mt][pt] = __builtin_amdgcn_mfma_f32_16x16x32_bf16(
                        af[mt], bfv[pt], acc[mt][pt], 0, 0, 0);
        }
        __syncthreads();
    }

    if constexpr (MODE == 1) {
        if (m0 < 512) {
            #pragma unroll
            for (int mt = 0; mt < 2; mt++) {
                int mch = m0 + wm * 32 + mt * 16 + lg * 4;
                float4 bs = *(const float4*)(bias + mch);
                #pragma unroll
                for (int pt = 0; pt < 4; pt++) {
                    int p = p0 + wp * 64 + pt * 16 + lm;
                    unsigned int u0 = pack2(acc[mt][pt][0] + bs.x, acc[mt][pt][1] + bs.y);
                    unsigned int u1 = pack2(acc[mt][pt][2] + bs.z, acc[mt][pt][3] + bs.w);
                    *(uint2*)(aux1 + ((size_t)(b * 4096 + p) * 512 + mch)) = make_uint2(u0, u1);
                }
            }
        } else {
            #pragma unroll
            for (int mt = 0; mt < 2; mt++) {
                #pragma unroll
                for (int r = 0; r < 4; r++) {
                    int m = m0 + wm * 32 + mt * 16 + lg * 4 + r;
                    float bsv = bias[m];
                    float* orow = vf32 + ((size_t)b * 256 + (m - 512)) * 4096 + p0 + wp * 64;
                    #pragma unroll
                    for (int pt = 0; pt < 4; pt++)
                        orow[pt * 16 + lm] = acc[mt][pt][r] + bsv;
                }
            }
        }
    } else if constexpr (MODE == 2) {
        #pragma unroll
        for (int mt = 0; mt < 2; mt++) {
            int ch = m0 + wm * 32 + mt * 16 + lg * 4;
            int head = ch >> 5, d = ch & 31;
            float4 bs = *(const float4*)(bias + ch);
            #pragma unroll
            for (int pt = 0; pt < 4; pt++) {
                int p = p0 + wp * 64 + pt * 16 + lm;
                unsigned int u0 = pack2((acc[mt][pt][0] + bs.x) * oscale,
                                        (acc[mt][pt][1] + bs.y) * oscale);
                unsigned int u1 = pack2((acc[mt][pt][2] + bs.z) * oscale,
                                        (acc[mt][pt][3] + bs.w) * oscale);
                *(uint2*)(aux1 + ((size_t)(b * 8 + head) * P + p) * 32 + d) = make_uint2(u0, u1);
            }
        }
    } else if constexpr (MODE == 3) {
        #pragma unroll
        for (int mt = 0; mt < 2; mt++) {
            int ch = m0 + wm * 32 + mt * 16 + lg * 4;
            if (ch < 256) {     // K -> p-major [bh][1024][32]
                int head = ch >> 5, d = ch & 31;
                float4 bs = *(const float4*)(bias + ch);
                #pragma unroll
                for (int pt = 0; pt < 4; pt++) {
                    int p = p0 + wp * 64 + pt * 16 + lm;
                    unsigned int u0 = pack2(acc[mt][pt][0] + bs.x, acc[mt][pt][1] + bs.y);
                    unsigned int u1 = pack2(acc[mt][pt][2] + bs.z, acc[mt][pt][3] + bs.w);
                    *(uint2*)(aux1 + ((size_t)(b * 8 + head) * P + p) * 32 + d) = make_uint2(u0, u1);
                }
            } else {            // V -> c-major [bh][32][1024], vperm'd positions
                int v = ch - 256;
                int head = v >> 5, d0 = v & 31;
                #pragma unroll
                for (int pt = 0; pt < 4; pt++) {
                    int p = p0 + wp * 64 + pt * 16 + lm;
                    int pos = (p & ~63) | vperm(p & 63);
                    #pragma unroll
                    for (int r = 0; r < 4; r++)
                        aux2[((size_t)(b * 8 + head) * 32 + d0 + r) * P + pos] =
                            f2bf(acc[mt][pt][r] + bias[ch + r]);
                }
            }
        }
    } else {
        #pragma unroll
        for (int mt = 0; mt < 2; mt++) {
            #pragma unroll
            for (int r = 0; r < 4; r++) {
                int m = m0 + wm * 32 + mt * 16 + lg * 4 + r;
                float bs = bias ? bias[m] : 0.f;
                float* orow = out + (size_t)b * OC * P + (size_t)m * P + p0 + wp * 64;
                #pragma unroll
                for (int pt = 0; pt < 4; pt++)
                    orow[pt * 16 + lm] = acc[mt][pt][r] + bs;
            }
        }
    }
}

// ---------------- local windowed attention, bf16 MFMA, fixed-max, LDS-free ----------------
// qkp: [B][4096][512] bf16 (Q ch 0-255, K ch 256-511); vf32: [B][256][4096] fp32.
// P stays in registers: PV A-frag chunk c = p[8c..8c+7]; V loaded in permuted key order.
__global__ __launch_bounds__(256) void local_attn_mfma(
    const unsigned short* __restrict__ qkp,
    const float* __restrict__ vf32,
    float* __restrict__ gx)
{
    int win = blockIdx.x;                  // b*512 + h*64 + gy*8 + gxc
    int gxc = win & 7, gy = (win >> 3) & 7, h = (win >> 6) & 7, b = win >> 9;
    int w = threadIdx.x >> 6, lane = threadIdx.x & 63;
    int m = lane & 15, g = lane >> 4;

    int rowbase = (gy * 8) * 64 + gxc * 8;   // pixel of window token 0
    const unsigned short* qkb = qkp + (size_t)b * 4096 * 512;
    const float* vbase = vf32 + (size_t)b * 256 * 4096;

    // Q-frag (B-op): query token w*16+m
    int tq = w * 16 + m;
    int pq = rowbase + (tq >> 3) * 64 + (tq & 7);
    v8s qf = *(const v8s*)(qkb + (size_t)pq * 512 + h * 32 + g * 8);

    // K-frags (A-op): key tokens kt*16+m
    v8s ka[4];
    #pragma unroll
    for (int kt = 0; kt < 4; kt++) {
        int tk = kt * 16 + m;
        int pk = rowbase + (tk >> 3) * 64 + (tk & 7);
        ka[kt] = *(const v8s*)(qkb + (size_t)pk * 512 + 256 + h * 32 + g * 8);
    }
    // V-frags (B-op of PV) in permuted key order: contract elem e of chunk c is
    // token (2c + (e>>2))*16 + g*4 + (e&3)  ->  two 4-pixel runs per frag.
    v8s vb[2][2];
    #pragma unroll
    for (int c = 0; c < 2; c++)
        #pragma unroll
        for (int dt = 0; dt < 2; dt++) {
            const float* vp = vbase + (size_t)(h * 32 + dt * 16 + m) * 4096
                              + rowbase + (4 * c + (g >> 1)) * 64 + (g & 1) * 4;
            vb[c][dt] = pack8(*(const float4*)vp, *(const float4*)(vp + 128));
        }

    const v4f zf = {0.f, 0.f, 0.f, 0.f};
    v4f s[4];
    #pragma unroll
    for (int kt = 0; kt < 4; kt++)
        s[kt] = __builtin_amdgcn_mfma_f32_16x16x32_bf16(ka[kt], qf, zf, 0, 0, 0);

    float p[16];
    float lsum = 0.f;
    #pragma unroll
    for (int kt = 0; kt < 4; kt++) {
        #pragma unroll
        for (int r = 0; r < 4; r++) {
            p[kt * 4 + r] = __expf(fmaf(s[kt][r], SCALE, -MFIX));
            lsum += p[kt * 4 + r];
        }
    }
    lsum += __shfl_xor(lsum, 16);
    lsum += __shfl_xor(lsum, 32);
    float inv = 1.f / lsum;

    v8s pa0 = pack8p(p), pa1 = pack8p(p + 8);
    v4f o0 = zf, o1 = zf;
    o0 = __builtin_amdgcn_mfma_f32_16x16x32_bf16(pa0, vb[0][0], o0, 0, 0, 0);
    o1 = __builtin_amdgcn_mfma_f32_16x16x32_bf16(pa0, vb[0][1], o1, 0, 0, 0);
    o0 = __builtin_amdgcn_mfma_f32_16x16x32_bf16(pa1, vb[1][0], o0, 0, 0, 0);
    o1 = __builtin_amdgcn_mfma_f32_16x16x32_bf16(pa1, vb[1][1], o1, 0, 0, 0);

    float invq[4];
    #pragma unroll
    for (int r = 0; r < 4; r++) invq[r] = __shfl(inv, g * 4 + r);

    int t0 = w * 16 + g * 4;
    int px0 = rowbase + (t0 >> 3) * 64 + (t0 & 7);
    float* op0 = gx + ((size_t)b * 256 + h * 32 + m) * 4096 + px0;
    *(float4*)op0 = make_float4(o0[0] * invq[0], o0[1] * invq[1], o0[2] * invq[2], o0[3] * invq[3]);
    float* op1 = gx + ((size_t)b * 256 + h * 32 + 16 + m) * 4096 + px0;
    *(float4*)op1 = make_float4(o1[0] * invq[0], o1[1] * invq[1], o1[2] * invq[2], o1[3] * invq[3]);
}

// ---------------- patch-merge layernorm (reads coalesced gxT, writes bf16 mn) ----------
__global__ __launch_bounds__(256) void patch_merge_ln2(
    const unsigned short* __restrict__ gxT,
    const float* __restrict__ lnw, const float* __restrict__ lnb,
    unsigned short* __restrict__ mn)
{
    int pix = blockIdx.x;
    int b = pix >> 10, op = pix & 1023;
    int oh = op >> 5, ow = op & 31;
    int t = threadIdx.x;
    const unsigned short* base = gxT + (size_t)b * 4096 * 256;
    float v[4];
    #pragma unroll
    for (int i = 0; i < 4; i++) {
        int h = 2 * oh + (i & 1);
        int w = 2 * ow + (i >> 1);
        v[i] = bf2f(base[(size_t)(h * 64 + w) * 256 + t]);
    }
    float s  = v[0] + v[1] + v[2] + v[3];
    float s2 = v[0]*v[0] + v[1]*v[1] + v[2]*v[2] + v[3]*v[3];
    __shared__ float ls[256], ls2[256];
    ls[t] = s; ls2[t] = s2; __syncthreads();
    for (int off = 128; off > 0; off >>= 1) {
        if (t < off) { ls[t] += ls[t + off]; ls2[t] += ls2[t + off]; }
        __syncthreads();
    }
    float mu  = ls[0] * (1.f / 1024.f);
    float var = ls2[0] * (1.f / 1024.f) - mu * mu;
    float r = rsqrtf(var + EPS_LN);
    unsigned short* orow = mn + (size_t)pix * 1024;
    #pragma unroll
    for (int i = 0; i < 4; i++) {
        int j = i * 256 + t;
        orow[j] = f2bf((v[i] - mu) * r * lnw[j] + lnb[j]);
    }
}

// ---------------- global attention, bf16 MFMA, fixed-max, LDS-free, fused epilogue ------
// qT: [B*8][4096][32] bf16 (SCALE folded); kT: [B*8][1024][32]; vT: [B*8][32][1024]
// (vperm'd key positions). Reads gxT, writes projT = bf16(gxT + O) p-major.
__global__ __launch_bounds__(256) void global_attn_mfma(
    const unsigned short* __restrict__ qT,
    const unsigned short* __restrict__ kT,
    const unsigned short* __restrict__ vT,
    const unsigned short* __restrict__ gxT,
    unsigned short* __restrict__ projT)
{
    int blk = blockIdx.x;
    int qt = blk & 63, h = (blk >> 6) & 7, b = blk >> 9;
    int bh = b * 8 + h;
    int w = threadIdx.x >> 6, lane = threadIdx.x & 63;
    int m = lane & 15, g = lane >> 4;
    int qbase = qt * 64 + w * 16;

    v8s qf = *(const v8s*)(qT + ((size_t)bh * 4096 + qbase + m) * 32 + g * 8);

    v4f o0 = {0.f, 0.f, 0.f, 0.f}, o1 = {0.f, 0.f, 0.f, 0.f};
    float l_run = 0.f;
    const v4f zf = {0.f, 0.f, 0.f, 0.f};

    const unsigned short* kbase = kT + ((size_t)bh * 1024 + m) * 32 + g * 8;
    const unsigned short* vbase = vT + ((size_t)bh * 32 + m) * 1024 + g * 8;

    #pragma unroll 2
    for (int t = 0; t < 16; t++) {
        int k0 = t * 64;
        const unsigned short* kp = kbase + k0 * 32;
        v8s ka0 = *(const v8s*)(kp);
        v8s ka1 = *(const v8s*)(kp + 16 * 32);
        v8s ka2 = *(const v8s*)(kp + 32 * 32);
        v8s ka3 = *(const v8s*)(kp + 48 * 32);
        v4f s[4];
        s[0] = __builtin_amdgcn_mfma_f32_16x16x32_bf16(ka0, qf, zf, 0, 0, 0);
        s[1] = __builtin_amdgcn_mfma_f32_16x16x32_bf16(ka1, qf, zf, 0, 0, 0);
        s[2] = __builtin_amdgcn_mfma_f32_16x16x32_bf16(ka2, qf, zf, 0, 0, 0);
        s[3] = __builtin_amdgcn_mfma_f32_16x16x32_bf16(ka3, qf, zf, 0, 0, 0);

        float p[16];
        #pragma unroll
        for (int kt = 0; kt < 4; kt++) {
            #pragma unroll
            for (int r = 0; r < 4; r++) {
                p[kt * 4 + r] = __expf(s[kt][r] - MFIX);
                l_run += p[kt * 4 + r];
            }
        }
        v8s pa0 = pack8p(p), pa1 = pack8p(p + 8);

        const unsigned short* vp = vbase + k0;
        v8s vb00 = *(const v8s*)(vp);
        v8s vb01 = *(const v8s*)(vp + 16 * 1024);
        v8s vb10 = *(const v8s*)(vp + 32);
        v8s vb11 = *(const v8s*)(vp + 32 + 16 * 1024);
        o0 = __builtin_amdgcn_mfma_f32_16x16x32_bf16(pa0, vb00, o0, 0, 0, 0);
        o1 = __builtin_amdgcn_mfma_f32_16x16x32_bf16(pa0, vb01, o1, 0, 0, 0);
        o0 = __builtin_amdgcn_mfma_f32_16x16x32_bf16(pa1, vb10, o0, 0, 0, 0);
        o1 = __builtin_amdgcn_mfma_f32_16x16x32_bf16(pa1, vb11, o1, 0, 0, 0);
    }

    float lf = l_run;
    lf += __shfl_xor(lf, 16);
    lf += __shfl_xor(lf, 32);
    float inv = 1.f / lf;
    float invq[4];
    #pragma unroll
    for (int r = 0; r < 4; r++) invq[r] = __shfl(inv, g * 4 + r);

    #pragma unroll
    for (int r = 0; r < 4; r++) {
        size_t row = ((size_t)b * 4096 + qbase + g * 4 + r) * 256 + h * 32;
        projT[row + m]      = f2bf(bf2f(gxT[row + m])      + o0[r] * invq[r]);
        projT[row + 16 + m] = f2bf(bf2f(gxT[row + 16 + m]) + o1[r] * invq[r]);
    }
}

// ---------------- launcher ----------------
extern "C" void kernel_launch(void* const* d_in, const int* in_sizes, int n_in,
                              void* d_out, int out_size, void* d_ws, size_t ws_size,
                              hipStream_t stream)
{
    const float* x           = (const float*)d_in[0];
    const float* norm_w      = (const float*)d_in[1];
    const float* norm_b      = (const float*)d_in[2];
    const float* qkv_w       = (const float*)d_in[3];
    const float* qkv_b       = (const float*)d_in[4];
    const float* proj_w      = (const float*)d_in[5];
    const float* proj_b      = (const float*)d_in[6];
    const float* grid_norm_w = (const float*)d_in[7];
    const float* grid_norm_b = (const float*)d_in[8];
    const float* pm_ln_w     = (const float*)d_in[9];
    const float* pm_ln_b     = (const float*)d_in[10];
    const float* pm_red_w    = (const float*)d_in[11];
    const float* ds_norm_w   = (const float*)d_in[12];
    const float* ds_norm_b   = (const float*)d_in[13];
    const float* q_w         = (const float*)d_in[14];
    const float* q_b         = (const float*)d_in[15];
    const float* kv_w        = (const float*)d_in[16];
    const float* kv_b        = (const float*)d_in[17];
    float* out = (float*)d_out;

    float* wsf = (float*)d_ws;
    // region A [0, 12.58M floats) — float-slot accounting, disjoint lifetimes:
    //   qkp    [0, 4,194,304)            bf16 [4][4096][512]  (steps 4-5)
    //   vf32   [4,194,304, 8,388,608)    fp32 [4][256][4096]  (steps 4-5)
    //   mnb    [0, 2,097,152)            bf16 [4096][1024]    (steps 8-9)
    //   kTu    [0, 524,288)              bf16 [32][1024][32]  (steps 12-14)
    //   vTu    [524,288, 1,048,576)      bf16 [32][32][1024]  (steps 12-14)
    //   pm     [2,097,152, 3,145,728)    fp32 [4][256][1024]  (steps 9-11)
    //   pmT    [3,145,728, 3,670,016)    bf16 [4][1024][256]  (steps 11-12)
    //   qTu    [10,485,760, 12,582,912)  bf16 [32][4096][32]  (steps 13-14)
    unsigned short* qkp   = (unsigned short*)(wsf);
    float* vf32           = wsf + 4194304;
    unsigned short* mnb   = (unsigned short*)(wsf);
    unsigned short* kTu   = (unsigned short*)(wsf);
    unsigned short* vTu   = (unsigned short*)(wsf + 524288);
    float* pm             = wsf + 2097152;
    unsigned short* pmT   = (unsigned short*)(wsf + 3145728);
    unsigned short* qTu   = (unsigned short*)(wsf + 10485760);
    // region B [12.58M,16.78M): gxbuf (steps 5-7); then projT (steps 14-15)
    float* gxbuf          = wsf + 12582912;
    unsigned short* projT = (unsigned short*)(wsf + 12582912);
    // region C [16.78M,18.78M): xT (steps 3-4), then gxT (steps 7-14)
    unsigned short* xT    = (unsigned short*)(wsf + 16777216);
    unsigned short* gxT   = (unsigned short*)(wsf + 16777216);
    // region D: small scratch + weights
    float* part   = wsf + 18874368;
    float* stats0 = part + 512;
    float* stats1 = stats0 + 8;
    float* stats2 = stats1 + 8;
    unsigned short* wbf   = (unsigned short*)(wsf + 18875392);
    unsigned short* wbf_qkv  = wbf;
    unsigned short* wbf_pm   = wbf + 196608;
    unsigned short* wbf_kv   = wbf + 458752;
    unsigned short* wbf_q    = wbf + 589824;
    unsigned short* wbf_proj = wbf + 655360;

    // 1. weights -> bf16
    cast_weights<<<704, 256, 0, stream>>>(qkv_w, pm_red_w, kv_w, q_w, proj_w, wbf);
    // 2. stats of x
    gn_partial<<<BATCH * 64, 256, 0, stream>>>(x, nullptr, 1048576, 64, part);
    gn_finalize<<<1, 64, 0, stream>>>(part, 64, 1.f / 1048576.f, EPS_GN, stats0, BATCH);
    // 3. xT = bf16(GN(x)) p-major
    tnc<<<dim3(64, 4, BATCH), 256, 0, stream>>>(x, nullptr, stats0, norm_w, norm_b, xT, 4096);
    // 4. qkv GEMM (MFMA) -> qkp (Q,K p-major bf16) + vf32 (V c-major fp32)
    gemm_bf16<1><<<dim3(32, 12, BATCH), 256, 0, stream>>>(
        xT, wbf_qkv, qkv_b, nullptr, qkp, nullptr, vf32, 256, 4096, 768, 1.f);
    // 5. local windowed attention (MFMA, LDS-free) -> gxbuf fp32 c-major
    local_attn_mfma<<<2048, 256, 0, stream>>>(qkp, vf32, gxbuf);
    // 6. stats of x+gx
    gn_partial<<<BATCH * 64, 256, 0, stream>>>(x, gxbuf, 1048576, 64, part);
    gn_finalize<<<1, 64, 0, stream>>>(part, 64, 1.f / 1048576.f, EPS_GN, stats1, BATCH);
    // 7. gxT = bf16(GN(x+gx)) p-major
    tnc<<<dim3(64, 4, BATCH), 256, 0, stream>>>(x, gxbuf, stats1, grid_norm_w, grid_norm_b, gxT, 4096);
    // 8. patch-merge LN -> mn bf16
    patch_merge_ln2<<<4096, 256, 0, stream>>>(gxT, pm_ln_w, pm_ln_b, mnb);
    // 9. patch-merge reduction GEMM (MFMA)
    gemm_bf16<0><<<dim3(8, 4, BATCH), 256, 0, stream>>>(
        mnb, wbf_pm, nullptr, pm, nullptr, nullptr, nullptr, 1024, 1024, 256, 1.f);
    // 10. stats of pm
    gn_partial<<<BATCH * 16, 256, 0, stream>>>(pm, nullptr, 262144, 16, part);
    gn_finalize<<<1, 64, 0, stream>>>(part, 16, 1.f / 262144.f, EPS_GN, stats2, BATCH);
    // 11. pmT = bf16(GN(pm)) p-major
    tnc<<<dim3(16, 4, BATCH), 256, 0, stream>>>(pm, nullptr, stats2, ds_norm_w, ds_norm_b, pmT, 1024);
    // 12. kv GEMM (MFMA) -> kTu (p-major) + vTu (c-major, vperm'd)
    gemm_bf16<3><<<dim3(8, 8, BATCH), 256, 0, stream>>>(
        pmT, wbf_kv, kv_b, nullptr, kTu, vTu, nullptr, 256, 1024, 512, 1.f);
    // 13. q GEMM (MFMA) -> qTu (head-split p-major, SCALE folded)
    gemm_bf16<2><<<dim3(32, 4, BATCH), 256, 0, stream>>>(
        gxT, wbf_q, q_b, nullptr, qTu, nullptr, nullptr, 256, 4096, 256, SCALE);
    // 14. global attention (MFMA, LDS-free) -> projT = bf16(gxT + O)
    global_attn_mfma<<<2048, 256, 0, stream>>>(qTu, kTu, vTu, gxT, projT);
    // 15. proj GEMM (MFMA) -> out
    gemm_bf16<0><<<dim3(32, 4, BATCH), 256, 0, stream>>>(
        projT, wbf_proj, proj_b, out, nullptr, nullptr, nullptr, 256, 4096, 256, 1.f);
}